// Round 18
// baseline (2867.764 us; speedup 1.0000x reference)
//
#include <hip/hip_runtime.h>
#include <hip/hip_bf16.h>

#define HD 256
#define WD 256
#define CH 256
#define NB 2
#define NPIX (NB*HD*WD)

typedef __attribute__((ext_vector_type(4))) float f32x4;
typedef __attribute__((ext_vector_type(8))) short h16x8;
typedef __attribute__((ext_vector_type(4))) short h16x4;
typedef __fp16 f16x2 __attribute__((ext_vector_type(2)));

union U16 { uint4 q; f16x2 h[4]; };
union U8h { uint2 u; f16x2 h[2]; };
union UPK { f16x2 h; unsigned u; };

__device__ __forceinline__ short f2h(float f){
  __fp16 h = (__fp16)f;
  return *(short*)&h;
}
__device__ __forceinline__ unsigned p2h(float a, float b){
  UPK P; P.h = __builtin_amdgcn_cvt_pkrtz(a, b);
  return P.u;
}

__device__ __forceinline__ f32x4 mfma_f16(h16x8 a, h16x8 b, f32x4 c){
  asm("v_mfma_f32_16x16x32_f16 %0, %1, %2, %0" : "+v"(c) : "v"(a), "v"(b));
  return c;
}

// ---------------- weight fp32 -> f16 ----------------
__global__ __launch_bounds__(256) void k_cvtw(const float* __restrict__ qkvw,
    const float* __restrict__ projw, const float* __restrict__ w1,
    const float* __restrict__ w2, short* __restrict__ out){
  int i = blockIdx.x*256 + threadIdx.x;
  float v;
  if (i < 196608) v = qkvw[i];
  else if (i < 262144) v = projw[i-196608];
  else if (i < 524288) v = w1[i-262144];
  else v = w2[i-524288];
  out[i] = f2h(v);
}

// ---------------- h fp32 -> f16 ----------------
__global__ __launch_bounds__(256) void k_cvth(const float* __restrict__ h, short* __restrict__ hh){
  int i = blockIdx.x*256 + threadIdx.x;
  const float4* p = ((const float4*)h) + (size_t)i*2;
  float4 a = p[0], b4 = p[1];
  U16 W;
  W.h[0] = __builtin_amdgcn_cvt_pkrtz(a.x, a.y);
  W.h[1] = __builtin_amdgcn_cvt_pkrtz(a.z, a.w);
  W.h[2] = __builtin_amdgcn_cvt_pkrtz(b4.x, b4.y);
  W.h[3] = __builtin_amdgcn_cvt_pkrtz(b4.z, b4.w);
  ((uint4*)hh)[i] = W.q;
}

// ---------------- transpose conv weights to channel-minor ----------------
__global__ __launch_bounds__(256) void k_prepw(const float* __restrict__ combw,
    const float* __restrict__ gw, const float* __restrict__ hw,
    const float* __restrict__ fw, float* __restrict__ wT){
  int i = blockIdx.x*256 + threadIdx.x;
  if (i < 25088){
    int wi = i>>9, r = i&511, ii = r>>8, o = r&255;
    wT[i] = combw[o*98 + ii*49 + wi];
  } else if (i < 37632){
    int j = i-25088; int wi = j>>8, c = j&255;
    wT[i] = gw[c*49 + wi];
  } else if (i < 50176){
    int j = i-37632; int wi = j>>8, c = j&255;
    wT[i] = hw[c*49 + wi];
  } else if (i < 52480){
    int j = i-50176; int tap = j>>8, r = j&255, oc = r>>2, ic = r&3;
    wT[i] = fw[oc*36 + ic*9 + tap];
  } else {
    int j = i-52480;                 // 0..25087
    int wi = j>>9, r2 = j&511;
    int o = r2>>1, ii = r2&1;
    ((__fp16*)wT)[104960 + j] = (__fp16)combw[o*98 + ii*49 + wi];
  }
}

// ---------------- depthwise 3x3 (NCHW in) + bias + relu + LN1 -> NHWC f16 ----------------
__global__ __launch_bounds__(256) void k_conv3(const float* __restrict__ x,
    const float* __restrict__ w, const float* __restrict__ bias,
    const float* __restrict__ g1, const float* __restrict__ b1,
    short* __restrict__ out){
  int bid = blockIdx.x;
  int xb = bid & 15, y = (bid>>4) & 255, b = bid>>12;
  int t = threadIdx.x;
  __shared__ float tile[16][268];
  int xx0 = xb*16;
  {
    int xi = t & 15, cg = t >> 4;
    int xxg = xx0 + xi;
    #pragma unroll
    for (int k=0;k<16;++k){
      int c = cg*16 + k;
      const float* xp = x + ((size_t)(b*CH + c)*HD)*WD;
      float acc = bias[c];
      #pragma unroll
      for (int dy=-1; dy<=1; ++dy){
        int yy = y+dy;
        if ((unsigned)yy >= HD) continue;
        #pragma unroll
        for (int dx=-1; dx<=1; ++dx){
          int x2 = xxg+dx;
          if ((unsigned)x2 >= WD) continue;
          acc += xp[yy*WD + x2] * w[c*9 + (dy+1)*3 + (dx+1)];
        }
      }
      tile[xi][c] = fmaxf(acc, 0.f);
    }
  }
  __syncthreads();
  {
    int px = t >> 4, cs = t & 15;
    float4 m[4];
    #pragma unroll
    for (int j=0;j<4;++j) m[j] = *(const float4*)(&tile[px][cs*16 + j*4]);
    float s = 0.f, q = 0.f;
    #pragma unroll
    for (int j=0;j<4;++j){
      s += m[j].x+m[j].y+m[j].z+m[j].w;
      q += m[j].x*m[j].x+m[j].y*m[j].y+m[j].z*m[j].z+m[j].w*m[j].w;
    }
    #pragma unroll
    for (int o=1;o<16;o<<=1){ s += __shfl_xor(s,o); q += __shfl_xor(q,o); }
    float mean = s*(1.f/CH);
    float r = rsqrtf(q*(1.f/CH) - mean*mean + 1e-5f);
    size_t n = (size_t)(b*HD + y)*WD + xx0 + px;
    short* op = out + n*CH + cs*16;
    U16 W0, W1;
    #pragma unroll
    for (int j=0;j<4;++j){
      float4 G = *(const float4*)(g1 + cs*16 + j*4);
      float4 Bb = *(const float4*)(b1 + cs*16 + j*4);
      float4 o4;
      o4.x = (m[j].x-mean)*r*G.x + Bb.x;
      o4.y = (m[j].y-mean)*r*G.y + Bb.y;
      o4.z = (m[j].z-mean)*r*G.z + Bb.z;
      o4.w = (m[j].w-mean)*r*G.w + Bb.w;
      f16x2 p0 = __builtin_amdgcn_cvt_pkrtz(o4.x, o4.y);
      f16x2 p1 = __builtin_amdgcn_cvt_pkrtz(o4.z, o4.w);
      if (j<2){ W0.h[2*j] = p0; W0.h[2*j+1] = p1; }
      else    { W1.h[2*(j-2)] = p0; W1.h[2*(j-2)+1] = p1; }
    }
    *(uint4*)op = W0.q;
    *(uint4*)(op+8) = W1.q;
  }
}

// ---------------- grouped 7x7 combine (f16 data, fdot2) + relu + LN2 + fsaLN ----------------
__global__ __launch_bounds__(256) void k_comb(const short* __restrict__ xcv,
    const short* __restrict__ hh, const short* __restrict__ wTh,
    const float* __restrict__ bias,
    const float* __restrict__ g2, const float* __restrict__ b2,
    const float* __restrict__ gf, const float* __restrict__ bfv,
    short* __restrict__ xch, short* __restrict__ ybuf){
  int bid = blockIdx.x;
  int xg = bid & 63, yb = (bid>>6) & 63, b = bid>>12;
  int wv = threadIdx.x>>6, lane = threadIdx.x & 63;
  int xx = xg*4 + wv, y0 = yb*4;
  const short* S = (lane < 32) ? xcv : hh;
  int cin = 8*(lane & 31);
  float4 bv = ((const float4*)bias)[lane];
  float4 acc[4];
  #pragma unroll
  for (int i=0;i<4;++i) acc[i] = bv;
  bool inty = (y0 >= 3) && (y0 <= HD-7);
  #pragma unroll 1
  for (int dx=0; dx<7; ++dx){
    int x2 = xx + dx - 3;
    bool vx = (unsigned)x2 < WD;
    uint4 r[10];
    if (vx && inty){
      const short* base = S + ((size_t)((b*HD + y0-3)*WD + x2))*CH + cin;
      #pragma unroll
      for (int k=0;k<10;++k)
        r[k] = *(const uint4*)(base + (size_t)k*WD*CH);
    } else {
      #pragma unroll
      for (int k=0;k<10;++k){
        int yy = y0 + k - 3;
        if (vx && (unsigned)yy < HD)
          r[k] = *(const uint4*)(S + ((size_t)((b*HD+yy)*WD + x2))*CH + cin);
        else r[k] = uint4{0,0,0,0};
      }
    }
    #pragma unroll
    for (int dy=0; dy<7; ++dy){
      int wi = dy*7 + dx;
      U16 wq; wq.q = ((const uint4*)wTh)[wi*64 + lane];
      #pragma unroll
      for (int yi=0; yi<4; ++yi){
        U16 d; d.q = r[yi+dy];
        acc[yi].x = __builtin_amdgcn_fdot2(d.h[0], wq.h[0], acc[yi].x, false);
        acc[yi].y = __builtin_amdgcn_fdot2(d.h[1], wq.h[1], acc[yi].y, false);
        acc[yi].z = __builtin_amdgcn_fdot2(d.h[2], wq.h[2], acc[yi].z, false);
        acc[yi].w = __builtin_amdgcn_fdot2(d.h[3], wq.h[3], acc[yi].w, false);
      }
    }
  }
  float4 G2 = ((const float4*)g2)[lane],  B2 = ((const float4*)b2)[lane];
  float4 GF = ((const float4*)gf)[lane],  BF = ((const float4*)bfv)[lane];
  #pragma unroll
  for (int yi=0; yi<4; ++yi){
    float4 v;
    v.x = fmaxf(acc[yi].x, 0.f); v.y = fmaxf(acc[yi].y, 0.f);
    v.z = fmaxf(acc[yi].z, 0.f); v.w = fmaxf(acc[yi].w, 0.f);
    float s = v.x+v.y+v.z+v.w;
    float q = v.x*v.x+v.y*v.y+v.z*v.z+v.w*v.w;
    #pragma unroll
    for (int o=1;o<64;o<<=1){ s += __shfl_xor(s,o); q += __shfl_xor(q,o); }
    float mean = s*(1.f/CH);
    float r = rsqrtf(q*(1.f/CH) - mean*mean + 1e-5f);
    float4 w4;
    w4.x = (v.x-mean)*r*G2.x + B2.x;
    w4.y = (v.y-mean)*r*G2.y + B2.y;
    w4.z = (v.z-mean)*r*G2.z + B2.z;
    w4.w = (v.w-mean)*r*G2.w + B2.w;
    size_t n = (size_t)((b*HD + y0+yi)*WD + xx);
    union { f16x2 h[2]; uint2 u; } P;
    P.h[0] = __builtin_amdgcn_cvt_pkrtz(w4.x, w4.y);
    P.h[1] = __builtin_amdgcn_cvt_pkrtz(w4.z, w4.w);
    *(uint2*)(xch + n*CH + 4*lane) = P.u;
    float s2 = w4.x+w4.y+w4.z+w4.w;
    float q2 = w4.x*w4.x+w4.y*w4.y+w4.z*w4.z+w4.w*w4.w;
    #pragma unroll
    for (int o=1;o<64;o<<=1){ s2 += __shfl_xor(s2,o); q2 += __shfl_xor(q2,o); }
    float m2 = s2*(1.f/CH);
    float r2 = rsqrtf(q2*(1.f/CH) - m2*m2 + 1e-5f);
    union { f16x2 h[2]; uint2 u; } Y;
    Y.h[0] = __builtin_amdgcn_cvt_pkrtz((w4.x-m2)*r2*GF.x + BF.x, (w4.y-m2)*r2*GF.y + BF.y);
    Y.h[1] = __builtin_amdgcn_cvt_pkrtz((w4.z-m2)*r2*GF.z + BF.z, (w4.w-m2)*r2*GF.w + BF.w);
    *(uint2*)(ybuf + n*CH + 4*lane) = Y.u;
  }
}

// ---------------- window attention + fused per-head proj + residual/LN3 (all f16 MFMA) ----------------
__global__ __launch_bounds__(256) void k_attn(const short* __restrict__ ybuf,
    const short* __restrict__ wqkv, const float* __restrict__ qkvb,
    const short* __restrict__ wproj, const float* __restrict__ pb,
    const __fp16* __restrict__ xc, const float* __restrict__ g3,
    const float* __restrict__ b3, short* __restrict__ zbuf){
  __shared__ short wlds[24576];
  __shared__ short qs[64][40];
  __shared__ short ksm[64][40];
  __shared__ short vT[32][72];
  __shared__ short o2[2][64][36];
  __shared__ float redS[64][4];
  __shared__ float redQ[64][4];
  int wid = blockIdx.x;
  int b = wid>>10, wy = (wid>>5)&31, wx = wid&31;
  int t = threadIdx.x, wv = t>>6, lane = t&63;
  int g = lane>>4, c = lane&15;

  h16x8 afr[8];
  {
    int tok = 16*wv + c;
    size_t n = (size_t)(b*HD + wy*8 + (tok>>3))*WD + wx*8 + (tok&7);
    const short* yp = ybuf + n*CH;
    #pragma unroll
    for (int ks=0;ks<8;++ks)
      afr[ks] = *(const h16x8*)(yp + ks*32 + g*8);
  }
  {
    const short* wsrc = wqkv;
    #pragma unroll
    for (int i=0;i<12;++i){
      int rr = 24*wv + 2*i;
      int row = rr + (lane>>5);
      int colb = (lane&31)<<4;
      const short* gp = wsrc + row*256 + ((colb ^ ((row&7)<<4))>>1);
      __builtin_amdgcn_global_load_lds(
        (const __attribute__((address_space(1))) void*)gp,
        (__attribute__((address_space(3))) void*)(wlds + rr*256),
        16, 0, 0);
    }
  }
  __syncthreads();

  int s0 = c + 32*(g&1), s1 = s0 + 16;
  bool hiSel = (g & 2);

  f32x4 acc[4][4];
  #pragma unroll
  for (int mt=0;mt<4;++mt)
    #pragma unroll
    for (int nt=0;nt<4;++nt) acc[mt][nt] = (f32x4){0.f,0.f,0.f,0.f};

  #pragma unroll 1
  for (int hd=0; hd<8; ++hd){
    int cur = hd & 1;
    f32x4 qacc[6];
    #pragma unroll
    for (int nt=0;nt<6;++nt) qacc[nt] = (f32x4){0.f,0.f,0.f,0.f};
    #pragma unroll
    for (int nt=0; nt<6; ++nt){
      int R = nt*16 + c;
      const short* wr = wlds + R*256;
      int sw = (R&7)<<3;
      #pragma unroll
      for (int ks=0; ks<8; ++ks){
        h16x8 bf = *(const h16x8*)(wr + ((ks*32 + g*8) ^ sw));
        qacc[nt] = mfma_f16(afr[ks], bf, qacc[nt]);
      }
    }
    #pragma unroll
    for (int nt=0; nt<6; ++nt){
      float bias = qkvb[hd*96 + nt*16 + c];
      if (nt<4){
        #pragma unroll
        for (int j=0;j<4;++j){
          short hv = f2h(qacc[nt][j] + bias);
          int tok = 16*wv + 4*g + j;
          if (nt<2) qs[tok][nt*16 + c] = hv;
          else      ksm[tok][(nt-2)*16 + c] = hv;
        }
      } else {
        uint2 pk;
        pk.x = p2h(qacc[nt][0] + bias, qacc[nt][1] + bias);
        pk.y = p2h(qacc[nt][2] + bias, qacc[nt][3] + bias);
        *(uint2*)(&vT[(nt-4)*16 + c][16*wv + 4*g]) = pk;
      }
    }
    __syncthreads();
    if (hd < 7){
      const short* wsrc = wqkv + (size_t)(hd+1)*24576;
      #pragma unroll
      for (int i=0;i<12;++i){
        int rr = 24*wv + 2*i;
        int row = rr + (lane>>5);
        int colb = (lane&31)<<4;
        const short* gp = wsrc + row*256 + ((colb ^ ((row&7)<<4))>>1);
        __builtin_amdgcn_global_load_lds(
          (const __attribute__((address_space(1))) void*)gp,
          (__attribute__((address_space(3))) void*)(wlds + rr*256),
          16, 0, 0);
      }
    }
    f32x4 sv[4];
    h16x8 qa = *(const h16x8*)(&qs[16*wv + c][g*8]);
    #pragma unroll
    for (int nt=0;nt<4;++nt){
      h16x8 kb = *(const h16x8*)(&ksm[nt*16 + c][g*8]);
      f32x4 z = (f32x4){0.f,0.f,0.f,0.f};
      sv[nt] = mfma_f16(kb, qa, z);
    }
    float mx = sv[0][0];
    #pragma unroll
    for (int nt=0;nt<4;++nt)
      #pragma unroll
      for (int j=0;j<4;++j) mx = fmaxf(mx, sv[nt][j]);
    mx = fmaxf(mx, __shfl_xor(mx, 16));
    mx = fmaxf(mx, __shfl_xor(mx, 32));
    float sm = 0.f;
    #pragma unroll
    for (int nt=0;nt<4;++nt)
      #pragma unroll
      for (int j=0;j<4;++j){
        float e = __expf((sv[nt][j]-mx)*0.17677669529663687f);
        sv[nt][j] = e; sm += e;
      }
    sm += __shfl_xor(sm, 16);
    sm += __shfl_xor(sm, 32);
    float inv = 1.f/sm;
    unsigned pkLo[4], pkHi[4];
    #pragma unroll
    for (int nt=0;nt<4;++nt){
      pkLo[nt] = p2h(sv[nt][0], sv[nt][1]);
      pkHi[nt] = p2h(sv[nt][2], sv[nt][3]);
    }
    h16x8 pa[2];
    #pragma unroll
    for (int k2=0;k2<2;++k2){
      int n0 = 2*k2, n1 = 2*k2+1;
      unsigned w0a = __shfl((int)pkLo[n0], s0), w0b = __shfl((int)pkLo[n1], s0);
      unsigned w1a = __shfl((int)pkHi[n0], s0), w1b = __shfl((int)pkHi[n1], s0);
      unsigned w2a = __shfl((int)pkLo[n0], s1), w2b = __shfl((int)pkLo[n1], s1);
      unsigned w3a = __shfl((int)pkHi[n0], s1), w3b = __shfl((int)pkHi[n1], s1);
      union { unsigned u[4]; h16x8 v; } U;
      U.u[0] = hiSel ? w0b : w0a;
      U.u[1] = hiSel ? w1b : w1a;
      U.u[2] = hiSel ? w2b : w2a;
      U.u[3] = hiSel ? w3b : w3a;
      pa[k2] = U.v;
    }
    f32x4 ov[2];
    ov[0] = (f32x4){0.f,0.f,0.f,0.f}; ov[1] = (f32x4){0.f,0.f,0.f,0.f};
    #pragma unroll
    for (int k2=0;k2<2;++k2){
      #pragma unroll
      for (int nt=0;nt<2;++nt){
        h16x8 vb = *(const h16x8*)(&vT[nt*16 + c][k2*32 + g*8]);
        ov[nt] = mfma_f16(pa[k2], vb, ov[nt]);
      }
    }
    #pragma unroll
    for (int j=0;j<4;++j){
      float invO = __shfl(inv, 4*g + j);
      int tok = 16*wv + 4*g + j;
      o2[cur][tok][c]      = f2h(ov[0][j]*invO);
      o2[cur][tok][16 + c] = f2h(ov[1][j]*invO);
    }
    __syncthreads();
    #pragma unroll
    for (int mt=0;mt<4;++mt){
      h16x8 a = *(const h16x8*)(&o2[cur][mt*16+c][g*8]);
      #pragma unroll
      for (int nt=0;nt<4;++nt){
        h16x8 bfr = *(const h16x8*)(wproj + (size_t)(wv*64 + nt*16 + c)*256 + hd*32 + g*8);
        acc[mt][nt] = mfma_f16(a, bfr, acc[mt][nt]);
      }
    }
  }
  // ---- epilogue: bias + residual(f16 xc) + relu + LN3 -> zbuf (f16) ----
  #pragma unroll
  for (int mt=0;mt<4;++mt){
    #pragma unroll
    for (int j=0;j<4;++j){
      int row_l = mt*16 + 4*g + j;
      size_t n = (size_t)(b*HD + wy*8 + (row_l>>3))*WD + wx*8 + (row_l&7);
      float ps_ = 0.f, pq_ = 0.f;
      #pragma unroll
      for (int nt=0;nt<4;++nt){
        int col = wv*64 + nt*16 + c;
        float v = acc[mt][nt][j] + pb[col] + (float)xc[n*CH + col];
        v = fmaxf(v, 0.f);
        acc[mt][nt][j] = v;
        ps_ += v; pq_ += v*v;
      }
      #pragma unroll
      for (int o=1;o<16;o<<=1){ ps_ += __shfl_xor(ps_,o); pq_ += __shfl_xor(pq_,o); }
      if (c==0){ redS[row_l][wv] = ps_; redQ[row_l][wv] = pq_; }
    }
  }
  __syncthreads();
  #pragma unroll
  for (int mt=0;mt<4;++mt){
    #pragma unroll
    for (int j=0;j<4;++j){
      int row_l = mt*16 + 4*g + j;
      size_t n = (size_t)(b*HD + wy*8 + (row_l>>3))*WD + wx*8 + (row_l&7);
      float st = redS[row_l][0]+redS[row_l][1]+redS[row_l][2]+redS[row_l][3];
      float qt = redQ[row_l][0]+redQ[row_l][1]+redQ[row_l][2]+redQ[row_l][3];
      float mean = st*(1.f/CH);
      float rs = rsqrtf(qt*(1.f/CH) - mean*mean + 1e-5f);
      #pragma unroll
      for (int nt=0;nt<4;++nt){
        int col = wv*64 + nt*16 + c;
        float y = (acc[mt][nt][j]-mean)*rs*g3[col] + b3[col];
        zbuf[n*CH + col] = f2h(y);
      }
    }
  }
}

// ---------------- fused MLP, barrier-free: wave owns 16 rows; hid rows are wave-private ----------------
__global__ __launch_bounds__(256) void k_mlp(const short* __restrict__ zbuf,
    const short* __restrict__ w1, const short* __restrict__ w2,
    const float* __restrict__ b1, const float* __restrict__ b2,
    __fp16* __restrict__ bsa){
  __shared__ short hid[64][140];   // wave wv uses rows [16wv,16wv+16) only
  int blk = blockIdx.x, t = threadIdx.x;
  int wv=t>>6, lane=t&63, g=lane>>4, c=lane&15;
  size_t m0 = (size_t)blk*64;
  int row = 16*wv + c;
  // A fragments (16 rows/wave) from global, held in registers for the whole kernel
  h16x8 afr[8];
  {
    const short* zp = zbuf + (m0 + row)*CH + g*8;
    #pragma unroll
    for (int ks=0;ks<8;++ks) afr[ks] = *(const h16x8*)(zp + ks*32);
  }
  f32x4 acc2[16];
  #pragma unroll
  for (int nt=0;nt<16;++nt) acc2[nt] = (f32x4){0.f,0.f,0.f,0.f};
  #pragma unroll 1
  for (int hc=0; hc<8; ++hc){
    // GEMM1: a1[nl] = z(16 rows) @ w1 cols [hc*128, hc*128+128)
    f32x4 a1[8];
    #pragma unroll
    for (int nl=0;nl<8;++nl) a1[nl] = (f32x4){0.f,0.f,0.f,0.f};
    #pragma unroll 1
    for (int ks=0;ks<8;++ks){
      #pragma unroll
      for (int nl=0;nl<8;++nl){
        int o = hc*128 + nl*16 + c;
        h16x8 bfr = *(const h16x8*)(w1 + (size_t)o*256 + ks*32 + g*8);
        a1[nl] = mfma_f16(afr[ks], bfr, a1[nl]);
      }
    }
    // gelu -> hid (wave-private rows; same-wave visibility via lgkmcnt only)
    #pragma unroll
    for (int nl=0;nl<8;++nl){
      int ol = nl*16 + c;
      float bias = b1[hc*128 + ol];
      #pragma unroll
      for (int j=0;j<4;++j){
        float v = a1[nl][j] + bias;
        float w = v*v;
        float tt = v*(1.5957691216f + 0.0713548162f*w);
        float e = __expf(-tt);
        float gv = v/(1.f + e);
        hid[16*wv + 4*g + j][ol] = f2h(gv);
      }
    }
    // GEMM2: acc2 += gelu(h) @ w2 K-slice [hc*128, hc*128+128)
    #pragma unroll 1
    for (int k2=0;k2<4;++k2){
      h16x8 ha = *(const h16x8*)(&hid[16*wv + c][k2*32 + g*8]);
      #pragma unroll
      for (int nt=0;nt<16;++nt){
        h16x8 bfr = *(const h16x8*)(w2 + (size_t)(nt*16+c)*1024 + hc*128 + k2*32 + g*8);
        acc2[nt] = mfma_f16(ha, bfr, acc2[nt]);
      }
    }
  }
  #pragma unroll
  for (int nt=0;nt<16;++nt){
    int col = nt*16 + c;
    float bias = b2[col];
    #pragma unroll
    for (int j=0;j<4;++j){
      int row_l = 16*wv + 4*g + j;
      bsa[(m0+row_l)*CH + col] = (__fp16)(acc2[nt][j] + bias);
    }
  }
}

// ---------------- depthwise 7x7 + bias + relu (f16 in -> f16 out) ----------------
__global__ __launch_bounds__(256) void k_dw7(const __fp16* __restrict__ src,
    const float* __restrict__ wT, const float* __restrict__ bias, __fp16* __restrict__ dst){
  int bid = blockIdx.x;
  int xg = bid & 63, yb = (bid>>6) & 31, b = bid>>11;
  int wv = threadIdx.x>>6, lane = threadIdx.x & 63;
  int xx = xg*4 + wv, y0 = yb*8;
  float4 bv = ((const float4*)bias)[lane];
  float4 acc[8];
  #pragma unroll
  for (int i=0;i<8;++i) acc[i] = bv;
  bool inty = (y0 >= 3) && (y0 <= HD-11);
  #pragma unroll 1
  for (int dx=0; dx<7; ++dx){
    int x2 = xx + dx - 3;
    bool vx = (unsigned)x2 < WD;
    float4 r[14];
    if (vx && inty){
      const __fp16* base = src + ((size_t)((b*HD + y0-3)*WD + x2))*CH + lane*4;
      #pragma unroll
      for (int k=0;k<14;++k){
        U8h H; H.u = *(const uint2*)(base + (size_t)k*WD*CH);
        r[k] = float4{(float)H.h[0][0], (float)H.h[0][1], (float)H.h[1][0], (float)H.h[1][1]};
      }
    } else {
      #pragma unroll
      for (int k=0;k<14;++k){
        int yy = y0 + k - 3;
        if (vx && (unsigned)yy < HD){
          U8h H; H.u = *(const uint2*)(src + ((size_t)((b*HD+yy)*WD + x2))*CH + lane*4);
          r[k] = float4{(float)H.h[0][0], (float)H.h[0][1], (float)H.h[1][0], (float)H.h[1][1]};
        } else r[k] = float4{0,0,0,0};
      }
    }
    #pragma unroll
    for (int dy=0; dy<7; ++dy){
      int wi = dy*7 + dx;
      float4 wv4 = ((const float4*)(wT + wi*256))[lane];
      #pragma unroll
      for (int yi=0; yi<8; ++yi){
        acc[yi].x += r[yi+dy].x * wv4.x;
        acc[yi].y += r[yi+dy].y * wv4.y;
        acc[yi].z += r[yi+dy].z * wv4.z;
        acc[yi].w += r[yi+dy].w * wv4.w;
      }
    }
  }
  #pragma unroll
  for (int yi=0; yi<8; ++yi){
    float4 o;
    o.x = fmaxf(acc[yi].x, 0.f); o.y = fmaxf(acc[yi].y, 0.f);
    o.z = fmaxf(acc[yi].z, 0.f); o.w = fmaxf(acc[yi].w, 0.f);
    size_t n = (size_t)((b*HD+y0+yi)*WD + xx);
    union { f16x2 h[2]; uint2 u; } P;
    P.h[0] = __builtin_amdgcn_cvt_pkrtz(o.x, o.y);
    P.h[1] = __builtin_amdgcn_cvt_pkrtz(o.z, o.w);
    *(uint2*)(dst + n*CH + lane*4) = P.u;
  }
}

// ---------------- merged: dw7-h (f16 in -> fp32 NHWC h_new) + convf (-> fp32 NCHW x_out) ----------------
__global__ __launch_bounds__(256) void k_dwf(const __fp16* __restrict__ src,
    const float* __restrict__ wTh7, const float* __restrict__ hbias,
    const float* __restrict__ wTf, const float* __restrict__ fbias,
    float* __restrict__ hout, float* __restrict__ xout){
  __shared__ float ot[4][8][65];
  int bid = blockIdx.x;
  int xg = bid & 63, yb = (bid>>6) & 31, b = bid>>11;
  int wv = threadIdx.x>>6, lane = threadIdx.x & 63;
  int xx = xg*4 + wv, y0 = yb*8;
  float4 bv = ((const float4*)hbias)[lane];
  float fbv = fbias[lane];
  float4 acc[8];
  float accf[8];
  #pragma unroll
  for (int i=0;i<8;++i){ acc[i] = bv; accf[i] = 0.f; }
  bool inty = (y0 >= 3) && (y0 <= HD-11);
  #pragma unroll 1
  for (int dx=0; dx<7; ++dx){
    int x2 = xx + dx - 3;
    bool vx = (unsigned)x2 < WD;
    float4 r[14];
    if (vx && inty){
      const __fp16* base = src + ((size_t)((b*HD + y0-3)*WD + x2))*CH + lane*4;
      #pragma unroll
      for (int k=0;k<14;++k){
        U8h H; H.u = *(const uint2*)(base + (size_t)k*WD*CH);
        r[k] = float4{(float)H.h[0][0], (float)H.h[0][1], (float)H.h[1][0], (float)H.h[1][1]};
      }
    } else {
      #pragma unroll
      for (int k=0;k<14;++k){
        int yy = y0 + k - 3;
        if (vx && (unsigned)yy < HD){
          U8h H; H.u = *(const uint2*)(src + ((size_t)((b*HD+yy)*WD + x2))*CH + lane*4);
          r[k] = float4{(float)H.h[0][0], (float)H.h[0][1], (float)H.h[1][0], (float)H.h[1][1]};
        } else r[k] = float4{0,0,0,0};
      }
    }
    #pragma unroll
    for (int dy=0; dy<7; ++dy){
      int wi = dy*7 + dx;
      float4 wv4 = ((const float4*)(wTh7 + wi*256))[lane];
      #pragma unroll
      for (int yi=0; yi<8; ++yi){
        acc[yi].x += r[yi+dy].x * wv4.x;
        acc[yi].y += r[yi+dy].y * wv4.y;
        acc[yi].z += r[yi+dy].z * wv4.z;
        acc[yi].w += r[yi+dy].w * wv4.w;
      }
    }
    if (dx >= 2 && dx <= 4){
      int fdx = dx - 2;
      #pragma unroll
      for (int dy=0; dy<3; ++dy){
        float4 w4 = ((const float4*)(wTf + (dy*3+fdx)*256))[lane];
        #pragma unroll
        for (int yi=0; yi<8; ++yi){
          float4 rv = r[yi+dy+2];
          accf[yi] += rv.x*w4.x + rv.y*w4.y + rv.z*w4.z + rv.w*w4.w;
        }
      }
    }
  }
  #pragma unroll
  for (int yi=0; yi<8; ++yi){
    float4 o;
    o.x = fmaxf(acc[yi].x, 0.f); o.y = fmaxf(acc[yi].y, 0.f);
    o.z = fmaxf(acc[yi].z, 0.f); o.w = fmaxf(acc[yi].w, 0.f);
    ((float4*)(hout + ((size_t)((b*HD+y0+yi)*WD + xx))*CH))[lane] = o;
  }
  #pragma unroll
  for (int yi=0; yi<8; ++yi) ot[wv][yi][lane] = fmaxf(accf[yi] + fbv, 0.f);
  __syncthreads();
  #pragma unroll
  for (int rep=0; rep<2; ++rep){
    int p = rep*256 + threadIdx.x;
    int oc = p>>3, yi = p&7;
    float4 v;
    v.x = ot[0][yi][oc]; v.y = ot[1][yi][oc]; v.z = ot[2][yi][oc]; v.w = ot[3][yi][oc];
    *(float4*)(xout + (((size_t)(b*64+oc))*HD + y0+yi)*WD + xg*4) = v;
  }
}

extern "C" void kernel_launch(void* const* d_in, const int* in_sizes, int n_in,
                              void* d_out, int out_size, void* d_ws, size_t ws_size,
                              hipStream_t stream) {
  const float* x      = (const float*)d_in[0];
  const float* hbuf   = (const float*)d_in[1];
  const float* conv_w = (const float*)d_in[2];
  const float* conv_b = (const float*)d_in[3];
  const float* comb_w = (const float*)d_in[4];
  const float* comb_b = (const float*)d_in[5];
  const float* ln1_g  = (const float*)d_in[6];
  const float* ln1_b  = (const float*)d_in[7];
  const float* ln2_g  = (const float*)d_in[8];
  const float* ln2_b  = (const float*)d_in[9];
  const float* ln3_g  = (const float*)d_in[10];
  const float* ln3_b  = (const float*)d_in[11];
  const float* fsa_g  = (const float*)d_in[12];
  const float* fsa_b  = (const float*)d_in[13];
  const float* qkv_w  = (const float*)d_in[14];
  const float* qkv_b  = (const float*)d_in[15];
  const float* proj_w = (const float*)d_in[16];
  const float* proj_b = (const float*)d_in[17];
  const float* mlp_w1 = (const float*)d_in[18];
  const float* mlp_b1 = (const float*)d_in[19];
  const float* mlp_w2 = (const float*)d_in[20];
  const float* mlp_b2 = (const float*)d_in[21];
  const float* convg_w= (const float*)d_in[22];
  const float* convg_b= (const float*)d_in[23];
  const float* convh_w= (const float*)d_in[24];
  const float* convh_b= (const float*)d_in[25];
  const float* convf_w= (const float*)d_in[26];
  const float* convf_b= (const float*)d_in[27];
  float* out = (float*)d_out;
  char* ws = (char*)d_ws;

  short* xcv  = (short*)(ws);
  short* hh   = (short*)(ws + 67108864);
  short* zbuf = (short*)(ws + 67108864);
  short* xch  = (short*)(ws + 134217728);
  __fp16* bsa = (__fp16*)(ws + 134217728);
  short* ybuf = (short*)(ws + 268435456);
  __fp16* gbuf= (__fp16*)(ws + 335544320);
  short* wb   = (short*)(ws + 469762048);
  float* wT   = (float*)(ws + 471334912);
  short* wTh  = (short*)wT + 104960;

  k_cvtw<<<3072,256,0,stream>>>(qkv_w, proj_w, mlp_w1, mlp_w2, wb);
  k_prepw<<<303,256,0,stream>>>(comb_w, convg_w, convh_w, convf_w, wT);
  k_cvth<<<16384,256,0,stream>>>(hbuf, hh);
  k_conv3<<<8192,256,0,stream>>>(x, conv_w, conv_b, ln1_g, ln1_b, xcv);
  k_comb<<<8192,256,0,stream>>>(xcv, hh, wTh, comb_b, ln2_g, ln2_b, fsa_g, fsa_b, xch, ybuf);
  k_attn<<<2048,256,0,stream>>>(ybuf, wb, qkv_b, wb+196608, proj_b, (const __fp16*)xch, ln3_g, ln3_b, zbuf);
  k_mlp<<<2048,256,0,stream>>>(zbuf, wb+262144, wb+524288, mlp_b1, mlp_b2, bsa);
  k_dw7<<<4096,256,0,stream>>>(bsa, wT+25088, convg_b, gbuf);
  k_dwf<<<4096,256,0,stream>>>(gbuf, wT+37632, convh_b, wT+50176, convf_b, out + 8388608, out);
}

// Round 19
// 1166.176 us; speedup vs baseline: 2.4591x; 2.4591x over previous
//
#include <hip/hip_runtime.h>
#include <hip/hip_bf16.h>

#define HD 256
#define WD 256
#define CH 256
#define NB 2
#define NPIX (NB*HD*WD)

typedef __attribute__((ext_vector_type(4))) float f32x4;
typedef __attribute__((ext_vector_type(8))) short h16x8;
typedef __attribute__((ext_vector_type(4))) short h16x4;
typedef __fp16 f16x2 __attribute__((ext_vector_type(2)));

union U16 { uint4 q; f16x2 h[4]; };
union U8h { uint2 u; f16x2 h[2]; };
union UPK { f16x2 h; unsigned u; };

__device__ __forceinline__ short f2h(float f){
  __fp16 h = (__fp16)f;
  return *(short*)&h;
}
__device__ __forceinline__ unsigned p2h(float a, float b){
  UPK P; P.h = __builtin_amdgcn_cvt_pkrtz(a, b);
  return P.u;
}

__device__ __forceinline__ f32x4 mfma_f16(h16x8 a, h16x8 b, f32x4 c){
  asm("v_mfma_f32_16x16x32_f16 %0, %1, %2, %0" : "+v"(c) : "v"(a), "v"(b));
  return c;
}

// ---------------- weight fp32 -> f16 ----------------
__global__ __launch_bounds__(256) void k_cvtw(const float* __restrict__ qkvw,
    const float* __restrict__ projw, const float* __restrict__ w1,
    const float* __restrict__ w2, short* __restrict__ out){
  int i = blockIdx.x*256 + threadIdx.x;
  float v;
  if (i < 196608) v = qkvw[i];
  else if (i < 262144) v = projw[i-196608];
  else if (i < 524288) v = w1[i-262144];
  else v = w2[i-524288];
  out[i] = f2h(v);
}

// ---------------- h fp32 -> f16 ----------------
__global__ __launch_bounds__(256) void k_cvth(const float* __restrict__ h, short* __restrict__ hh){
  int i = blockIdx.x*256 + threadIdx.x;
  const float4* p = ((const float4*)h) + (size_t)i*2;
  float4 a = p[0], b4 = p[1];
  U16 W;
  W.h[0] = __builtin_amdgcn_cvt_pkrtz(a.x, a.y);
  W.h[1] = __builtin_amdgcn_cvt_pkrtz(a.z, a.w);
  W.h[2] = __builtin_amdgcn_cvt_pkrtz(b4.x, b4.y);
  W.h[3] = __builtin_amdgcn_cvt_pkrtz(b4.z, b4.w);
  ((uint4*)hh)[i] = W.q;
}

// ---------------- transpose conv weights to channel-minor ----------------
__global__ __launch_bounds__(256) void k_prepw(const float* __restrict__ combw,
    const float* __restrict__ gw, const float* __restrict__ hw,
    const float* __restrict__ fw, float* __restrict__ wT){
  int i = blockIdx.x*256 + threadIdx.x;
  if (i < 25088){
    int wi = i>>9, r = i&511, ii = r>>8, o = r&255;
    wT[i] = combw[o*98 + ii*49 + wi];
  } else if (i < 37632){
    int j = i-25088; int wi = j>>8, c = j&255;
    wT[i] = gw[c*49 + wi];
  } else if (i < 50176){
    int j = i-37632; int wi = j>>8, c = j&255;
    wT[i] = hw[c*49 + wi];
  } else if (i < 52480){
    int j = i-50176; int tap = j>>8, r = j&255, oc = r>>2, ic = r&3;
    wT[i] = fw[oc*36 + ic*9 + tap];
  } else {
    int j = i-52480;                 // 0..25087
    int wi = j>>9, r2 = j&511;
    int o = r2>>1, ii = r2&1;
    ((__fp16*)wT)[104960 + j] = (__fp16)combw[o*98 + ii*49 + wi];
  }
}

// ---------------- depthwise 3x3 (NCHW in) + bias + relu + LN1 -> NHWC f16 ----------------
__global__ __launch_bounds__(256) void k_conv3(const float* __restrict__ x,
    const float* __restrict__ w, const float* __restrict__ bias,
    const float* __restrict__ g1, const float* __restrict__ b1,
    short* __restrict__ out){
  int bid = blockIdx.x;
  int xb = bid & 15, y = (bid>>4) & 255, b = bid>>12;
  int t = threadIdx.x;
  __shared__ float tile[16][268];
  int xx0 = xb*16;
  {
    int xi = t & 15, cg = t >> 4;
    int xxg = xx0 + xi;
    #pragma unroll
    for (int k=0;k<16;++k){
      int c = cg*16 + k;
      const float* xp = x + ((size_t)(b*CH + c)*HD)*WD;
      float acc = bias[c];
      #pragma unroll
      for (int dy=-1; dy<=1; ++dy){
        int yy = y+dy;
        if ((unsigned)yy >= HD) continue;
        #pragma unroll
        for (int dx=-1; dx<=1; ++dx){
          int x2 = xxg+dx;
          if ((unsigned)x2 >= WD) continue;
          acc += xp[yy*WD + x2] * w[c*9 + (dy+1)*3 + (dx+1)];
        }
      }
      tile[xi][c] = fmaxf(acc, 0.f);
    }
  }
  __syncthreads();
  {
    int px = t >> 4, cs = t & 15;
    float4 m[4];
    #pragma unroll
    for (int j=0;j<4;++j) m[j] = *(const float4*)(&tile[px][cs*16 + j*4]);
    float s = 0.f, q = 0.f;
    #pragma unroll
    for (int j=0;j<4;++j){
      s += m[j].x+m[j].y+m[j].z+m[j].w;
      q += m[j].x*m[j].x+m[j].y*m[j].y+m[j].z*m[j].z+m[j].w*m[j].w;
    }
    #pragma unroll
    for (int o=1;o<16;o<<=1){ s += __shfl_xor(s,o); q += __shfl_xor(q,o); }
    float mean = s*(1.f/CH);
    float r = rsqrtf(q*(1.f/CH) - mean*mean + 1e-5f);
    size_t n = (size_t)(b*HD + y)*WD + xx0 + px;
    short* op = out + n*CH + cs*16;
    U16 W0, W1;
    #pragma unroll
    for (int j=0;j<4;++j){
      float4 G = *(const float4*)(g1 + cs*16 + j*4);
      float4 Bb = *(const float4*)(b1 + cs*16 + j*4);
      float4 o4;
      o4.x = (m[j].x-mean)*r*G.x + Bb.x;
      o4.y = (m[j].y-mean)*r*G.y + Bb.y;
      o4.z = (m[j].z-mean)*r*G.z + Bb.z;
      o4.w = (m[j].w-mean)*r*G.w + Bb.w;
      f16x2 p0 = __builtin_amdgcn_cvt_pkrtz(o4.x, o4.y);
      f16x2 p1 = __builtin_amdgcn_cvt_pkrtz(o4.z, o4.w);
      if (j<2){ W0.h[2*j] = p0; W0.h[2*j+1] = p1; }
      else    { W1.h[2*(j-2)] = p0; W1.h[2*(j-2)+1] = p1; }
    }
    *(uint4*)op = W0.q;
    *(uint4*)(op+8) = W1.q;
  }
}

// ---------------- grouped 7x7 combine (f16 data, fdot2) + relu + LN2 + fsaLN ----------------
__global__ __launch_bounds__(256) void k_comb(const short* __restrict__ xcv,
    const short* __restrict__ hh, const short* __restrict__ wTh,
    const float* __restrict__ bias,
    const float* __restrict__ g2, const float* __restrict__ b2,
    const float* __restrict__ gf, const float* __restrict__ bfv,
    short* __restrict__ xch, short* __restrict__ ybuf){
  int bid = blockIdx.x;
  int xg = bid & 63, yb = (bid>>6) & 63, b = bid>>12;
  int wv = threadIdx.x>>6, lane = threadIdx.x & 63;
  int xx = xg*4 + wv, y0 = yb*4;
  const short* S = (lane < 32) ? xcv : hh;
  int cin = 8*(lane & 31);
  float4 bv = ((const float4*)bias)[lane];
  float4 acc[4];
  #pragma unroll
  for (int i=0;i<4;++i) acc[i] = bv;
  bool inty = (y0 >= 3) && (y0 <= HD-7);
  #pragma unroll 1
  for (int dx=0; dx<7; ++dx){
    int x2 = xx + dx - 3;
    bool vx = (unsigned)x2 < WD;
    uint4 r[10];
    if (vx && inty){
      const short* base = S + ((size_t)((b*HD + y0-3)*WD + x2))*CH + cin;
      #pragma unroll
      for (int k=0;k<10;++k)
        r[k] = *(const uint4*)(base + (size_t)k*WD*CH);
    } else {
      #pragma unroll
      for (int k=0;k<10;++k){
        int yy = y0 + k - 3;
        if (vx && (unsigned)yy < HD)
          r[k] = *(const uint4*)(S + ((size_t)((b*HD+yy)*WD + x2))*CH + cin);
        else r[k] = uint4{0,0,0,0};
      }
    }
    #pragma unroll
    for (int dy=0; dy<7; ++dy){
      int wi = dy*7 + dx;
      U16 wq; wq.q = ((const uint4*)wTh)[wi*64 + lane];
      #pragma unroll
      for (int yi=0; yi<4; ++yi){
        U16 d; d.q = r[yi+dy];
        acc[yi].x = __builtin_amdgcn_fdot2(d.h[0], wq.h[0], acc[yi].x, false);
        acc[yi].y = __builtin_amdgcn_fdot2(d.h[1], wq.h[1], acc[yi].y, false);
        acc[yi].z = __builtin_amdgcn_fdot2(d.h[2], wq.h[2], acc[yi].z, false);
        acc[yi].w = __builtin_amdgcn_fdot2(d.h[3], wq.h[3], acc[yi].w, false);
      }
    }
  }
  float4 G2 = ((const float4*)g2)[lane],  B2 = ((const float4*)b2)[lane];
  float4 GF = ((const float4*)gf)[lane],  BF = ((const float4*)bfv)[lane];
  #pragma unroll
  for (int yi=0; yi<4; ++yi){
    float4 v;
    v.x = fmaxf(acc[yi].x, 0.f); v.y = fmaxf(acc[yi].y, 0.f);
    v.z = fmaxf(acc[yi].z, 0.f); v.w = fmaxf(acc[yi].w, 0.f);
    float s = v.x+v.y+v.z+v.w;
    float q = v.x*v.x+v.y*v.y+v.z*v.z+v.w*v.w;
    #pragma unroll
    for (int o=1;o<64;o<<=1){ s += __shfl_xor(s,o); q += __shfl_xor(q,o); }
    float mean = s*(1.f/CH);
    float r = rsqrtf(q*(1.f/CH) - mean*mean + 1e-5f);
    float4 w4;
    w4.x = (v.x-mean)*r*G2.x + B2.x;
    w4.y = (v.y-mean)*r*G2.y + B2.y;
    w4.z = (v.z-mean)*r*G2.z + B2.z;
    w4.w = (v.w-mean)*r*G2.w + B2.w;
    size_t n = (size_t)((b*HD + y0+yi)*WD + xx);
    union { f16x2 h[2]; uint2 u; } P;
    P.h[0] = __builtin_amdgcn_cvt_pkrtz(w4.x, w4.y);
    P.h[1] = __builtin_amdgcn_cvt_pkrtz(w4.z, w4.w);
    *(uint2*)(xch + n*CH + 4*lane) = P.u;
    float s2 = w4.x+w4.y+w4.z+w4.w;
    float q2 = w4.x*w4.x+w4.y*w4.y+w4.z*w4.z+w4.w*w4.w;
    #pragma unroll
    for (int o=1;o<64;o<<=1){ s2 += __shfl_xor(s2,o); q2 += __shfl_xor(q2,o); }
    float m2 = s2*(1.f/CH);
    float r2 = rsqrtf(q2*(1.f/CH) - m2*m2 + 1e-5f);
    union { f16x2 h[2]; uint2 u; } Y;
    Y.h[0] = __builtin_amdgcn_cvt_pkrtz((w4.x-m2)*r2*GF.x + BF.x, (w4.y-m2)*r2*GF.y + BF.y);
    Y.h[1] = __builtin_amdgcn_cvt_pkrtz((w4.z-m2)*r2*GF.z + BF.z, (w4.w-m2)*r2*GF.w + BF.w);
    *(uint2*)(ybuf + n*CH + 4*lane) = Y.u;
  }
}

// ---------------- window attention + fused per-head proj + residual/LN3 (all f16 MFMA) ----------------
__global__ __launch_bounds__(256) void k_attn(const short* __restrict__ ybuf,
    const short* __restrict__ wqkv, const float* __restrict__ qkvb,
    const short* __restrict__ wproj, const float* __restrict__ pb,
    const __fp16* __restrict__ xc, const float* __restrict__ g3,
    const float* __restrict__ b3, short* __restrict__ zbuf){
  __shared__ short wlds[24576];
  __shared__ short qs[64][40];
  __shared__ short ksm[64][40];
  __shared__ short vT[32][72];
  __shared__ short o2[2][64][36];
  __shared__ float redS[64][4];
  __shared__ float redQ[64][4];
  int wid = blockIdx.x;
  int b = wid>>10, wy = (wid>>5)&31, wx = wid&31;
  int t = threadIdx.x, wv = t>>6, lane = t&63;
  int g = lane>>4, c = lane&15;

  h16x8 afr[8];
  {
    int tok = 16*wv + c;
    size_t n = (size_t)(b*HD + wy*8 + (tok>>3))*WD + wx*8 + (tok&7);
    const short* yp = ybuf + n*CH;
    #pragma unroll
    for (int ks=0;ks<8;++ks)
      afr[ks] = *(const h16x8*)(yp + ks*32 + g*8);
  }
  {
    const short* wsrc = wqkv;
    #pragma unroll
    for (int i=0;i<12;++i){
      int rr = 24*wv + 2*i;
      int row = rr + (lane>>5);
      int colb = (lane&31)<<4;
      const short* gp = wsrc + row*256 + ((colb ^ ((row&7)<<4))>>1);
      __builtin_amdgcn_global_load_lds(
        (const __attribute__((address_space(1))) void*)gp,
        (__attribute__((address_space(3))) void*)(wlds + rr*256),
        16, 0, 0);
    }
  }
  __syncthreads();

  int s0 = c + 32*(g&1), s1 = s0 + 16;
  bool hiSel = (g & 2);

  f32x4 acc[4][4];
  #pragma unroll
  for (int mt=0;mt<4;++mt)
    #pragma unroll
    for (int nt=0;nt<4;++nt) acc[mt][nt] = (f32x4){0.f,0.f,0.f,0.f};

  #pragma unroll 1
  for (int hd=0; hd<8; ++hd){
    int cur = hd & 1;
    f32x4 qacc[6];
    #pragma unroll
    for (int nt=0;nt<6;++nt) qacc[nt] = (f32x4){0.f,0.f,0.f,0.f};
    #pragma unroll
    for (int nt=0; nt<6; ++nt){
      int R = nt*16 + c;
      const short* wr = wlds + R*256;
      int sw = (R&7)<<3;
      #pragma unroll
      for (int ks=0; ks<8; ++ks){
        h16x8 bf = *(const h16x8*)(wr + ((ks*32 + g*8) ^ sw));
        qacc[nt] = mfma_f16(afr[ks], bf, qacc[nt]);
      }
    }
    #pragma unroll
    for (int nt=0; nt<6; ++nt){
      float bias = qkvb[hd*96 + nt*16 + c];
      if (nt<4){
        #pragma unroll
        for (int j=0;j<4;++j){
          short hv = f2h(qacc[nt][j] + bias);
          int tok = 16*wv + 4*g + j;
          if (nt<2) qs[tok][nt*16 + c] = hv;
          else      ksm[tok][(nt-2)*16 + c] = hv;
        }
      } else {
        uint2 pk;
        pk.x = p2h(qacc[nt][0] + bias, qacc[nt][1] + bias);
        pk.y = p2h(qacc[nt][2] + bias, qacc[nt][3] + bias);
        *(uint2*)(&vT[(nt-4)*16 + c][16*wv + 4*g]) = pk;
      }
    }
    __syncthreads();
    if (hd < 7){
      const short* wsrc = wqkv + (size_t)(hd+1)*24576;
      #pragma unroll
      for (int i=0;i<12;++i){
        int rr = 24*wv + 2*i;
        int row = rr + (lane>>5);
        int colb = (lane&31)<<4;
        const short* gp = wsrc + row*256 + ((colb ^ ((row&7)<<4))>>1);
        __builtin_amdgcn_global_load_lds(
          (const __attribute__((address_space(1))) void*)gp,
          (__attribute__((address_space(3))) void*)(wlds + rr*256),
          16, 0, 0);
      }
    }
    f32x4 sv[4];
    h16x8 qa = *(const h16x8*)(&qs[16*wv + c][g*8]);
    #pragma unroll
    for (int nt=0;nt<4;++nt){
      h16x8 kb = *(const h16x8*)(&ksm[nt*16 + c][g*8]);
      f32x4 z = (f32x4){0.f,0.f,0.f,0.f};
      sv[nt] = mfma_f16(kb, qa, z);
    }
    float mx = sv[0][0];
    #pragma unroll
    for (int nt=0;nt<4;++nt)
      #pragma unroll
      for (int j=0;j<4;++j) mx = fmaxf(mx, sv[nt][j]);
    mx = fmaxf(mx, __shfl_xor(mx, 16));
    mx = fmaxf(mx, __shfl_xor(mx, 32));
    float sm = 0.f;
    #pragma unroll
    for (int nt=0;nt<4;++nt)
      #pragma unroll
      for (int j=0;j<4;++j){
        float e = __expf((sv[nt][j]-mx)*0.17677669529663687f);
        sv[nt][j] = e; sm += e;
      }
    sm += __shfl_xor(sm, 16);
    sm += __shfl_xor(sm, 32);
    float inv = 1.f/sm;
    unsigned pkLo[4], pkHi[4];
    #pragma unroll
    for (int nt=0;nt<4;++nt){
      pkLo[nt] = p2h(sv[nt][0], sv[nt][1]);
      pkHi[nt] = p2h(sv[nt][2], sv[nt][3]);
    }
    h16x8 pa[2];
    #pragma unroll
    for (int k2=0;k2<2;++k2){
      int n0 = 2*k2, n1 = 2*k2+1;
      unsigned w0a = __shfl((int)pkLo[n0], s0), w0b = __shfl((int)pkLo[n1], s0);
      unsigned w1a = __shfl((int)pkHi[n0], s0), w1b = __shfl((int)pkHi[n1], s0);
      unsigned w2a = __shfl((int)pkLo[n0], s1), w2b = __shfl((int)pkLo[n1], s1);
      unsigned w3a = __shfl((int)pkHi[n0], s1), w3b = __shfl((int)pkHi[n1], s1);
      union { unsigned u[4]; h16x8 v; } U;
      U.u[0] = hiSel ? w0b : w0a;
      U.u[1] = hiSel ? w1b : w1a;
      U.u[2] = hiSel ? w2b : w2a;
      U.u[3] = hiSel ? w3b : w3a;
      pa[k2] = U.v;
    }
    f32x4 ov[2];
    ov[0] = (f32x4){0.f,0.f,0.f,0.f}; ov[1] = (f32x4){0.f,0.f,0.f,0.f};
    #pragma unroll
    for (int k2=0;k2<2;++k2){
      #pragma unroll
      for (int nt=0;nt<2;++nt){
        h16x8 vb = *(const h16x8*)(&vT[nt*16 + c][k2*32 + g*8]);
        ov[nt] = mfma_f16(pa[k2], vb, ov[nt]);
      }
    }
    #pragma unroll
    for (int j=0;j<4;++j){
      float invO = __shfl(inv, 4*g + j);
      int tok = 16*wv + 4*g + j;
      o2[cur][tok][c]      = f2h(ov[0][j]*invO);
      o2[cur][tok][16 + c] = f2h(ov[1][j]*invO);
    }
    __syncthreads();
    #pragma unroll
    for (int mt=0;mt<4;++mt){
      h16x8 a = *(const h16x8*)(&o2[cur][mt*16+c][g*8]);
      #pragma unroll
      for (int nt=0;nt<4;++nt){
        h16x8 bfr = *(const h16x8*)(wproj + (size_t)(wv*64 + nt*16 + c)*256 + hd*32 + g*8);
        acc[mt][nt] = mfma_f16(a, bfr, acc[mt][nt]);
      }
    }
  }
  // ---- epilogue: bias + residual(f16 xc) + relu + LN3 -> zbuf (f16) ----
  #pragma unroll
  for (int mt=0;mt<4;++mt){
    #pragma unroll
    for (int j=0;j<4;++j){
      int row_l = mt*16 + 4*g + j;
      size_t n = (size_t)(b*HD + wy*8 + (row_l>>3))*WD + wx*8 + (row_l&7);
      float ps_ = 0.f, pq_ = 0.f;
      #pragma unroll
      for (int nt=0;nt<4;++nt){
        int col = wv*64 + nt*16 + c;
        float v = acc[mt][nt][j] + pb[col] + (float)xc[n*CH + col];
        v = fmaxf(v, 0.f);
        acc[mt][nt][j] = v;
        ps_ += v; pq_ += v*v;
      }
      #pragma unroll
      for (int o=1;o<16;o<<=1){ ps_ += __shfl_xor(ps_,o); pq_ += __shfl_xor(pq_,o); }
      if (c==0){ redS[row_l][wv] = ps_; redQ[row_l][wv] = pq_; }
    }
  }
  __syncthreads();
  #pragma unroll
  for (int mt=0;mt<4;++mt){
    #pragma unroll
    for (int j=0;j<4;++j){
      int row_l = mt*16 + 4*g + j;
      size_t n = (size_t)(b*HD + wy*8 + (row_l>>3))*WD + wx*8 + (row_l&7);
      float st = redS[row_l][0]+redS[row_l][1]+redS[row_l][2]+redS[row_l][3];
      float qt = redQ[row_l][0]+redQ[row_l][1]+redQ[row_l][2]+redQ[row_l][3];
      float mean = st*(1.f/CH);
      float rs = rsqrtf(qt*(1.f/CH) - mean*mean + 1e-5f);
      #pragma unroll
      for (int nt=0;nt<4;++nt){
        int col = wv*64 + nt*16 + c;
        float y = (acc[mt][nt][j]-mean)*rs*g3[col] + b3[col];
        zbuf[n*CH + col] = f2h(y);
      }
    }
  }
}

// ---------------- fused MLP: gelu(z@w1^T+b1)@w2^T+b2 -> f16 (R17 known-good) ----------------
__global__ __launch_bounds__(256) void k_mlp(const short* __restrict__ zbuf,
    const short* __restrict__ w1, const short* __restrict__ w2,
    const float* __restrict__ b1, const float* __restrict__ b2,
    __fp16* __restrict__ bsa){
  __shared__ short zt[16384];      // [64][256], byte col ^= (row&7)<<4
  __shared__ short hid[64][140];   // 280B stride == 6 banks mod 32
  int blk = blockIdx.x, t = threadIdx.x;
  int wv=t>>6, lane=t&63, g=lane>>4, c=lane&15;
  size_t m0 = (size_t)blk*64;
  {
    const short* zsrc = zbuf + m0*CH;
    #pragma unroll
    for (int i=0;i<8;++i){
      int rr = 16*wv + 2*i;
      int row = rr + (lane>>5);
      int colb = (lane&31)<<4;
      const short* gp = zsrc + row*256 + ((colb ^ ((row&7)<<4))>>1);
      __builtin_amdgcn_global_load_lds(
        (const __attribute__((address_space(1))) void*)gp,
        (__attribute__((address_space(3))) void*)(zt + rr*256),
        16, 0, 0);
    }
  }
  __syncthreads();
  f32x4 acc2[4][4];
  #pragma unroll
  for (int mt=0;mt<4;++mt)
    #pragma unroll
    for (int nt=0;nt<4;++nt) acc2[mt][nt] = (f32x4){0.f,0.f,0.f,0.f};
  #pragma unroll 1
  for (int hc=0; hc<8; ++hc){
    f32x4 a1[4][2];
    #pragma unroll
    for (int mt=0;mt<4;++mt){ a1[mt][0]=(f32x4){0.f,0.f,0.f,0.f}; a1[mt][1]=(f32x4){0.f,0.f,0.f,0.f}; }
    #pragma unroll 1
    for (int ks=0;ks<8;++ks){
      h16x8 a[4];
      #pragma unroll
      for (int mt=0;mt<4;++mt){
        int R = mt*16 + c;
        a[mt] = *(const h16x8*)(zt + R*256 + ((ks*32 + g*8) ^ ((R&7)<<3)));
      }
      #pragma unroll
      for (int nl=0;nl<2;++nl){
        int o = hc*128 + (wv*2+nl)*16 + c;
        h16x8 bfr = *(const h16x8*)(w1 + (size_t)o*256 + ks*32 + g*8);
        #pragma unroll
        for (int mt=0;mt<4;++mt)
          a1[mt][nl] = mfma_f16(a[mt], bfr, a1[mt][nl]);
      }
    }
    __syncthreads();   // A: prev hc's GEMM2 reads of hid complete
    #pragma unroll
    for (int mt=0;mt<4;++mt)
      #pragma unroll
      for (int nl=0;nl<2;++nl){
        int ol = (wv*2+nl)*16 + c;
        float bias = b1[hc*128 + ol];
        #pragma unroll
        for (int j=0;j<4;++j){
          float v = a1[mt][nl][j] + bias;
          float w = v*v;
          float tt = v*(1.5957691216f + 0.0713548162f*w);
          float e = __expf(-tt);
          float gv = v/(1.f + e);
          hid[mt*16 + 4*g + j][ol] = f2h(gv);
        }
      }
    __syncthreads();   // B: hid visible
    #pragma unroll 1
    for (int k2=0;k2<4;++k2){
      h16x8 a[4];
      #pragma unroll
      for (int mt=0;mt<4;++mt) a[mt] = *(const h16x8*)(&hid[mt*16+c][k2*32+g*8]);
      #pragma unroll
      for (int nt=0;nt<4;++nt){
        h16x8 bfr = *(const h16x8*)(w2 + (size_t)(wv*64+nt*16+c)*1024 + hc*128 + k2*32 + g*8);
        #pragma unroll
        for (int mt=0;mt<4;++mt)
          acc2[mt][nt] = mfma_f16(a[mt], bfr, acc2[mt][nt]);
      }
    }
  }
  #pragma unroll
  for (int mt=0;mt<4;++mt)
    #pragma unroll
    for (int nt=0;nt<4;++nt){
      int col = wv*64 + nt*16 + c;
      #pragma unroll
      for (int j=0;j<4;++j){
        int row_l = mt*16 + 4*g + j;
        bsa[(m0+row_l)*CH + col] = (__fp16)(acc2[mt][nt][j] + b2[col]);
      }
    }
}

// ---------------- depthwise 7x7 + bias + relu (f16 in -> f16 out) ----------------
__global__ __launch_bounds__(256) void k_dw7(const __fp16* __restrict__ src,
    const float* __restrict__ wT, const float* __restrict__ bias, __fp16* __restrict__ dst){
  int bid = blockIdx.x;
  int xg = bid & 63, yb = (bid>>6) & 31, b = bid>>11;
  int wv = threadIdx.x>>6, lane = threadIdx.x & 63;
  int xx = xg*4 + wv, y0 = yb*8;
  float4 bv = ((const float4*)bias)[lane];
  float4 acc[8];
  #pragma unroll
  for (int i=0;i<8;++i) acc[i] = bv;
  bool inty = (y0 >= 3) && (y0 <= HD-11);
  #pragma unroll 1
  for (int dx=0; dx<7; ++dx){
    int x2 = xx + dx - 3;
    bool vx = (unsigned)x2 < WD;
    float4 r[14];
    if (vx && inty){
      const __fp16* base = src + ((size_t)((b*HD + y0-3)*WD + x2))*CH + lane*4;
      #pragma unroll
      for (int k=0;k<14;++k){
        U8h H; H.u = *(const uint2*)(base + (size_t)k*WD*CH);
        r[k] = float4{(float)H.h[0][0], (float)H.h[0][1], (float)H.h[1][0], (float)H.h[1][1]};
      }
    } else {
      #pragma unroll
      for (int k=0;k<14;++k){
        int yy = y0 + k - 3;
        if (vx && (unsigned)yy < HD){
          U8h H; H.u = *(const uint2*)(src + ((size_t)((b*HD+yy)*WD + x2))*CH + lane*4);
          r[k] = float4{(float)H.h[0][0], (float)H.h[0][1], (float)H.h[1][0], (float)H.h[1][1]};
        } else r[k] = float4{0,0,0,0};
      }
    }
    #pragma unroll
    for (int dy=0; dy<7; ++dy){
      int wi = dy*7 + dx;
      float4 wv4 = ((const float4*)(wT + wi*256))[lane];
      #pragma unroll
      for (int yi=0; yi<8; ++yi){
        acc[yi].x += r[yi+dy].x * wv4.x;
        acc[yi].y += r[yi+dy].y * wv4.y;
        acc[yi].z += r[yi+dy].z * wv4.z;
        acc[yi].w += r[yi+dy].w * wv4.w;
      }
    }
  }
  #pragma unroll
  for (int yi=0; yi<8; ++yi){
    float4 o;
    o.x = fmaxf(acc[yi].x, 0.f); o.y = fmaxf(acc[yi].y, 0.f);
    o.z = fmaxf(acc[yi].z, 0.f); o.w = fmaxf(acc[yi].w, 0.f);
    size_t n = (size_t)((b*HD+y0+yi)*WD + xx);
    union { f16x2 h[2]; uint2 u; } P;
    P.h[0] = __builtin_amdgcn_cvt_pkrtz(o.x, o.y);
    P.h[1] = __builtin_amdgcn_cvt_pkrtz(o.z, o.w);
    *(uint2*)(dst + n*CH + lane*4) = P.u;
  }
}

// ---------------- merged: dw7-h (f16 in -> fp32 NHWC h_new) + convf (-> fp32 NCHW x_out) ----------------
__global__ __launch_bounds__(256) void k_dwf(const __fp16* __restrict__ src,
    const float* __restrict__ wTh7, const float* __restrict__ hbias,
    const float* __restrict__ wTf, const float* __restrict__ fbias,
    float* __restrict__ hout, float* __restrict__ xout){
  __shared__ float ot[4][8][65];
  int bid = blockIdx.x;
  int xg = bid & 63, yb = (bid>>6) & 31, b = bid>>11;
  int wv = threadIdx.x>>6, lane = threadIdx.x & 63;
  int xx = xg*4 + wv, y0 = yb*8;
  float4 bv = ((const float4*)hbias)[lane];
  float fbv = fbias[lane];
  float4 acc[8];
  float accf[8];
  #pragma unroll
  for (int i=0;i<8;++i){ acc[i] = bv; accf[i] = 0.f; }
  bool inty = (y0 >= 3) && (y0 <= HD-11);
  #pragma unroll 1
  for (int dx=0; dx<7; ++dx){
    int x2 = xx + dx - 3;
    bool vx = (unsigned)x2 < WD;
    float4 r[14];
    if (vx && inty){
      const __fp16* base = src + ((size_t)((b*HD + y0-3)*WD + x2))*CH + lane*4;
      #pragma unroll
      for (int k=0;k<14;++k){
        U8h H; H.u = *(const uint2*)(base + (size_t)k*WD*CH);
        r[k] = float4{(float)H.h[0][0], (float)H.h[0][1], (float)H.h[1][0], (float)H.h[1][1]};
      }
    } else {
      #pragma unroll
      for (int k=0;k<14;++k){
        int yy = y0 + k - 3;
        if (vx && (unsigned)yy < HD){
          U8h H; H.u = *(const uint2*)(src + ((size_t)((b*HD+yy)*WD + x2))*CH + lane*4);
          r[k] = float4{(float)H.h[0][0], (float)H.h[0][1], (float)H.h[1][0], (float)H.h[1][1]};
        } else r[k] = float4{0,0,0,0};
      }
    }
    #pragma unroll
    for (int dy=0; dy<7; ++dy){
      int wi = dy*7 + dx;
      float4 wv4 = ((const float4*)(wTh7 + wi*256))[lane];
      #pragma unroll
      for (int yi=0; yi<8; ++yi){
        acc[yi].x += r[yi+dy].x * wv4.x;
        acc[yi].y += r[yi+dy].y * wv4.y;
        acc[yi].z += r[yi+dy].z * wv4.z;
        acc[yi].w += r[yi+dy].w * wv4.w;
      }
    }
    if (dx >= 2 && dx <= 4){
      int fdx = dx - 2;
      #pragma unroll
      for (int dy=0; dy<3; ++dy){
        float4 w4 = ((const float4*)(wTf + (dy*3+fdx)*256))[lane];
        #pragma unroll
        for (int yi=0; yi<8; ++yi){
          float4 rv = r[yi+dy+2];
          accf[yi] += rv.x*w4.x + rv.y*w4.y + rv.z*w4.z + rv.w*w4.w;
        }
      }
    }
  }
  #pragma unroll
  for (int yi=0; yi<8; ++yi){
    float4 o;
    o.x = fmaxf(acc[yi].x, 0.f); o.y = fmaxf(acc[yi].y, 0.f);
    o.z = fmaxf(acc[yi].z, 0.f); o.w = fmaxf(acc[yi].w, 0.f);
    ((float4*)(hout + ((size_t)((b*HD+y0+yi)*WD + xx))*CH))[lane] = o;
  }
  #pragma unroll
  for (int yi=0; yi<8; ++yi) ot[wv][yi][lane] = fmaxf(accf[yi] + fbv, 0.f);
  __syncthreads();
  #pragma unroll
  for (int rep=0; rep<2; ++rep){
    int p = rep*256 + threadIdx.x;
    int oc = p>>3, yi = p&7;
    float4 v;
    v.x = ot[0][yi][oc]; v.y = ot[1][yi][oc]; v.z = ot[2][yi][oc]; v.w = ot[3][yi][oc];
    *(float4*)(xout + (((size_t)(b*64+oc))*HD + y0+yi)*WD + xg*4) = v;
  }
}

extern "C" void kernel_launch(void* const* d_in, const int* in_sizes, int n_in,
                              void* d_out, int out_size, void* d_ws, size_t ws_size,
                              hipStream_t stream) {
  const float* x      = (const float*)d_in[0];
  const float* hbuf   = (const float*)d_in[1];
  const float* conv_w = (const float*)d_in[2];
  const float* conv_b = (const float*)d_in[3];
  const float* comb_w = (const float*)d_in[4];
  const float* comb_b = (const float*)d_in[5];
  const float* ln1_g  = (const float*)d_in[6];
  const float* ln1_b  = (const float*)d_in[7];
  const float* ln2_g  = (const float*)d_in[8];
  const float* ln2_b  = (const float*)d_in[9];
  const float* ln3_g  = (const float*)d_in[10];
  const float* ln3_b  = (const float*)d_in[11];
  const float* fsa_g  = (const float*)d_in[12];
  const float* fsa_b  = (const float*)d_in[13];
  const float* qkv_w  = (const float*)d_in[14];
  const float* qkv_b  = (const float*)d_in[15];
  const float* proj_w = (const float*)d_in[16];
  const float* proj_b = (const float*)d_in[17];
  const float* mlp_w1 = (const float*)d_in[18];
  const float* mlp_b1 = (const float*)d_in[19];
  const float* mlp_w2 = (const float*)d_in[20];
  const float* mlp_b2 = (const float*)d_in[21];
  const float* convg_w= (const float*)d_in[22];
  const float* convg_b= (const float*)d_in[23];
  const float* convh_w= (const float*)d_in[24];
  const float* convh_b= (const float*)d_in[25];
  const float* convf_w= (const float*)d_in[26];
  const float* convf_b= (const float*)d_in[27];
  float* out = (float*)d_out;
  char* ws = (char*)d_ws;

  short* xcv  = (short*)(ws);
  short* hh   = (short*)(ws + 67108864);
  short* zbuf = (short*)(ws + 67108864);
  short* xch  = (short*)(ws + 134217728);
  __fp16* bsa = (__fp16*)(ws + 134217728);
  short* ybuf = (short*)(ws + 268435456);
  __fp16* gbuf= (__fp16*)(ws + 335544320);
  short* wb   = (short*)(ws + 469762048);
  float* wT   = (float*)(ws + 471334912);
  short* wTh  = (short*)wT + 104960;

  k_cvtw<<<3072,256,0,stream>>>(qkv_w, proj_w, mlp_w1, mlp_w2, wb);
  k_prepw<<<303,256,0,stream>>>(comb_w, convg_w, convh_w, convf_w, wT);
  k_cvth<<<16384,256,0,stream>>>(hbuf, hh);
  k_conv3<<<8192,256,0,stream>>>(x, conv_w, conv_b, ln1_g, ln1_b, xcv);
  k_comb<<<8192,256,0,stream>>>(xcv, hh, wTh, comb_b, ln2_g, ln2_b, fsa_g, fsa_b, xch, ybuf);
  k_attn<<<2048,256,0,stream>>>(ybuf, wb, qkv_b, wb+196608, proj_b, (const __fp16*)xch, ln3_g, ln3_b, zbuf);
  k_mlp<<<2048,256,0,stream>>>(zbuf, wb+262144, wb+524288, mlp_b1, mlp_b2, bsa);
  k_dw7<<<4096,256,0,stream>>>(bsa, wT+25088, convg_b, gbuf);
  k_dwf<<<4096,256,0,stream>>>(gbuf, wT+37632, convh_b, wT+50176, convf_b, out + 8388608, out);
}

// Round 20
// 1154.334 us; speedup vs baseline: 2.4843x; 1.0103x over previous
//
#include <hip/hip_runtime.h>
#include <hip/hip_bf16.h>

#define HD 256
#define WD 256
#define CH 256
#define NB 2
#define NPIX (NB*HD*WD)

typedef __attribute__((ext_vector_type(4))) float f32x4;
typedef __attribute__((ext_vector_type(8))) short h16x8;
typedef __attribute__((ext_vector_type(4))) short h16x4;
typedef __fp16 f16x2 __attribute__((ext_vector_type(2)));

union U16 { uint4 q; f16x2 h[4]; };
union U8h { uint2 u; f16x2 h[2]; };
union UPK { f16x2 h; unsigned u; };

__device__ __forceinline__ short f2h(float f){
  __fp16 h = (__fp16)f;
  return *(short*)&h;
}
__device__ __forceinline__ unsigned p2h(float a, float b){
  UPK P; P.h = __builtin_amdgcn_cvt_pkrtz(a, b);
  return P.u;
}

__device__ __forceinline__ f32x4 mfma_f16(h16x8 a, h16x8 b, f32x4 c){
  asm("v_mfma_f32_16x16x32_f16 %0, %1, %2, %0" : "+v"(c) : "v"(a), "v"(b));
  return c;
}

// ---------------- merged prep: h->f16 | gemm weights->f16 | conv weight transpose ----------------
__global__ __launch_bounds__(256) void k_prep(const float* __restrict__ qkvw,
    const float* __restrict__ projw, const float* __restrict__ w1,
    const float* __restrict__ w2, short* __restrict__ wout,
    const float* __restrict__ combw, const float* __restrict__ gw,
    const float* __restrict__ hw, const float* __restrict__ fw,
    float* __restrict__ wT, const float* __restrict__ h, short* __restrict__ hh){
  int bid = blockIdx.x, t = threadIdx.x;
  if (bid < 16384){                      // h fp32 -> f16
    int i = bid*256 + t;
    const float4* p = ((const float4*)h) + (size_t)i*2;
    float4 a = p[0], b4 = p[1];
    U16 W;
    W.h[0] = __builtin_amdgcn_cvt_pkrtz(a.x, a.y);
    W.h[1] = __builtin_amdgcn_cvt_pkrtz(a.z, a.w);
    W.h[2] = __builtin_amdgcn_cvt_pkrtz(b4.x, b4.y);
    W.h[3] = __builtin_amdgcn_cvt_pkrtz(b4.z, b4.w);
    ((uint4*)hh)[i] = W.q;
  } else if (bid < 19456){               // gemm weights fp32 -> f16
    int i = (bid-16384)*256 + t;
    float v;
    if (i < 196608) v = qkvw[i];
    else if (i < 262144) v = projw[i-196608];
    else if (i < 524288) v = w1[i-262144];
    else v = w2[i-524288];
    wout[i] = f2h(v);
  } else {                               // conv weight transpose
    int i = (bid-19456)*256 + t;
    if (i < 25088){
      int wi = i>>9, r = i&511, ii = r>>8, o = r&255;
      wT[i] = combw[o*98 + ii*49 + wi];
    } else if (i < 37632){
      int j = i-25088; int wi = j>>8, c = j&255;
      wT[i] = gw[c*49 + wi];
    } else if (i < 50176){
      int j = i-37632; int wi = j>>8, c = j&255;
      wT[i] = hw[c*49 + wi];
    } else if (i < 52480){
      int j = i-50176; int tap = j>>8, r = j&255, oc = r>>2, ic = r&3;
      wT[i] = fw[oc*36 + ic*9 + tap];
    } else {
      int j = i-52480;                 // 0..25087
      int wi = j>>9, r2 = j&511;
      int o = r2>>1, ii = r2&1;
      ((__fp16*)wT)[104960 + j] = (__fp16)combw[o*98 + ii*49 + wi];
    }
  }
}

// ---------------- depthwise 3x3 (NCHW in) + bias + relu + LN1 -> NHWC f16 ----------------
__global__ __launch_bounds__(256) void k_conv3(const float* __restrict__ x,
    const float* __restrict__ w, const float* __restrict__ bias,
    const float* __restrict__ g1, const float* __restrict__ b1,
    short* __restrict__ out){
  int bid = blockIdx.x;
  int xb = bid & 15, y = (bid>>4) & 255, b = bid>>12;
  int t = threadIdx.x;
  __shared__ float tile[16][268];
  int xx0 = xb*16;
  {
    int xi = t & 15, cg = t >> 4;
    int xxg = xx0 + xi;
    #pragma unroll
    for (int k=0;k<16;++k){
      int c = cg*16 + k;
      const float* xp = x + ((size_t)(b*CH + c)*HD)*WD;
      float acc = bias[c];
      #pragma unroll
      for (int dy=-1; dy<=1; ++dy){
        int yy = y+dy;
        if ((unsigned)yy >= HD) continue;
        #pragma unroll
        for (int dx=-1; dx<=1; ++dx){
          int x2 = xxg+dx;
          if ((unsigned)x2 >= WD) continue;
          acc += xp[yy*WD + x2] * w[c*9 + (dy+1)*3 + (dx+1)];
        }
      }
      tile[xi][c] = fmaxf(acc, 0.f);
    }
  }
  __syncthreads();
  {
    int px = t >> 4, cs = t & 15;
    float4 m[4];
    #pragma unroll
    for (int j=0;j<4;++j) m[j] = *(const float4*)(&tile[px][cs*16 + j*4]);
    float s = 0.f, q = 0.f;
    #pragma unroll
    for (int j=0;j<4;++j){
      s += m[j].x+m[j].y+m[j].z+m[j].w;
      q += m[j].x*m[j].x+m[j].y*m[j].y+m[j].z*m[j].z+m[j].w*m[j].w;
    }
    #pragma unroll
    for (int o=1;o<16;o<<=1){ s += __shfl_xor(s,o); q += __shfl_xor(q,o); }
    float mean = s*(1.f/CH);
    float r = rsqrtf(q*(1.f/CH) - mean*mean + 1e-5f);
    size_t n = (size_t)(b*HD + y)*WD + xx0 + px;
    short* op = out + n*CH + cs*16;
    U16 W0, W1;
    #pragma unroll
    for (int j=0;j<4;++j){
      float4 G = *(const float4*)(g1 + cs*16 + j*4);
      float4 Bb = *(const float4*)(b1 + cs*16 + j*4);
      float4 o4;
      o4.x = (m[j].x-mean)*r*G.x + Bb.x;
      o4.y = (m[j].y-mean)*r*G.y + Bb.y;
      o4.z = (m[j].z-mean)*r*G.z + Bb.z;
      o4.w = (m[j].w-mean)*r*G.w + Bb.w;
      f16x2 p0 = __builtin_amdgcn_cvt_pkrtz(o4.x, o4.y);
      f16x2 p1 = __builtin_amdgcn_cvt_pkrtz(o4.z, o4.w);
      if (j<2){ W0.h[2*j] = p0; W0.h[2*j+1] = p1; }
      else    { W1.h[2*(j-2)] = p0; W1.h[2*(j-2)+1] = p1; }
    }
    *(uint4*)op = W0.q;
    *(uint4*)(op+8) = W1.q;
  }
}

// ---------------- grouped 7x7 combine (f16 data, fdot2) + relu + LN2 + fsaLN ----------------
__global__ __launch_bounds__(256) void k_comb(const short* __restrict__ xcv,
    const short* __restrict__ hh, const short* __restrict__ wTh,
    const float* __restrict__ bias,
    const float* __restrict__ g2, const float* __restrict__ b2,
    const float* __restrict__ gf, const float* __restrict__ bfv,
    short* __restrict__ xch, short* __restrict__ ybuf){
  int bid = blockIdx.x;
  int xg = bid & 63, yb = (bid>>6) & 63, b = bid>>12;
  int wv = threadIdx.x>>6, lane = threadIdx.x & 63;
  int xx = xg*4 + wv, y0 = yb*4;
  const short* S = (lane < 32) ? xcv : hh;
  int cin = 8*(lane & 31);
  float4 bv = ((const float4*)bias)[lane];
  float4 acc[4];
  #pragma unroll
  for (int i=0;i<4;++i) acc[i] = bv;
  bool inty = (y0 >= 3) && (y0 <= HD-7);
  #pragma unroll 1
  for (int dx=0; dx<7; ++dx){
    int x2 = xx + dx - 3;
    bool vx = (unsigned)x2 < WD;
    uint4 r[10];
    if (vx && inty){
      const short* base = S + ((size_t)((b*HD + y0-3)*WD + x2))*CH + cin;
      #pragma unroll
      for (int k=0;k<10;++k)
        r[k] = *(const uint4*)(base + (size_t)k*WD*CH);
    } else {
      #pragma unroll
      for (int k=0;k<10;++k){
        int yy = y0 + k - 3;
        if (vx && (unsigned)yy < HD)
          r[k] = *(const uint4*)(S + ((size_t)((b*HD+yy)*WD + x2))*CH + cin);
        else r[k] = uint4{0,0,0,0};
      }
    }
    #pragma unroll
    for (int dy=0; dy<7; ++dy){
      int wi = dy*7 + dx;
      U16 wq; wq.q = ((const uint4*)wTh)[wi*64 + lane];
      #pragma unroll
      for (int yi=0; yi<4; ++yi){
        U16 d; d.q = r[yi+dy];
        acc[yi].x = __builtin_amdgcn_fdot2(d.h[0], wq.h[0], acc[yi].x, false);
        acc[yi].y = __builtin_amdgcn_fdot2(d.h[1], wq.h[1], acc[yi].y, false);
        acc[yi].z = __builtin_amdgcn_fdot2(d.h[2], wq.h[2], acc[yi].z, false);
        acc[yi].w = __builtin_amdgcn_fdot2(d.h[3], wq.h[3], acc[yi].w, false);
      }
    }
  }
  float4 G2 = ((const float4*)g2)[lane],  B2 = ((const float4*)b2)[lane];
  float4 GF = ((const float4*)gf)[lane],  BF = ((const float4*)bfv)[lane];
  #pragma unroll
  for (int yi=0; yi<4; ++yi){
    float4 v;
    v.x = fmaxf(acc[yi].x, 0.f); v.y = fmaxf(acc[yi].y, 0.f);
    v.z = fmaxf(acc[yi].z, 0.f); v.w = fmaxf(acc[yi].w, 0.f);
    float s = v.x+v.y+v.z+v.w;
    float q = v.x*v.x+v.y*v.y+v.z*v.z+v.w*v.w;
    #pragma unroll
    for (int o=1;o<64;o<<=1){ s += __shfl_xor(s,o); q += __shfl_xor(q,o); }
    float mean = s*(1.f/CH);
    float r = rsqrtf(q*(1.f/CH) - mean*mean + 1e-5f);
    float4 w4;
    w4.x = (v.x-mean)*r*G2.x + B2.x;
    w4.y = (v.y-mean)*r*G2.y + B2.y;
    w4.z = (v.z-mean)*r*G2.z + B2.z;
    w4.w = (v.w-mean)*r*G2.w + B2.w;
    size_t n = (size_t)((b*HD + y0+yi)*WD + xx);
    union { f16x2 h[2]; uint2 u; } P;
    P.h[0] = __builtin_amdgcn_cvt_pkrtz(w4.x, w4.y);
    P.h[1] = __builtin_amdgcn_cvt_pkrtz(w4.z, w4.w);
    *(uint2*)(xch + n*CH + 4*lane) = P.u;
    float s2 = w4.x+w4.y+w4.z+w4.w;
    float q2 = w4.x*w4.x+w4.y*w4.y+w4.z*w4.z+w4.w*w4.w;
    #pragma unroll
    for (int o=1;o<64;o<<=1){ s2 += __shfl_xor(s2,o); q2 += __shfl_xor(q2,o); }
    float m2 = s2*(1.f/CH);
    float r2 = rsqrtf(q2*(1.f/CH) - m2*m2 + 1e-5f);
    union { f16x2 h[2]; uint2 u; } Y;
    Y.h[0] = __builtin_amdgcn_cvt_pkrtz((w4.x-m2)*r2*GF.x + BF.x, (w4.y-m2)*r2*GF.y + BF.y);
    Y.h[1] = __builtin_amdgcn_cvt_pkrtz((w4.z-m2)*r2*GF.z + BF.z, (w4.w-m2)*r2*GF.w + BF.w);
    *(uint2*)(ybuf + n*CH + 4*lane) = Y.u;
  }
}

// ---------------- window attention + fused per-head proj + residual/LN3 (all f16 MFMA) ----------------
__global__ __launch_bounds__(256) void k_attn(const short* __restrict__ ybuf,
    const short* __restrict__ wqkv, const float* __restrict__ qkvb,
    const short* __restrict__ wproj, const float* __restrict__ pb,
    const __fp16* __restrict__ xc, const float* __restrict__ g3,
    const float* __restrict__ b3, short* __restrict__ zbuf){
  __shared__ short wlds[24576];
  __shared__ short qs[64][40];
  __shared__ short ksm[64][40];
  __shared__ short vT[32][72];
  __shared__ short o2[2][64][36];
  __shared__ float redS[64][4];
  __shared__ float redQ[64][4];
  int wid = blockIdx.x;
  int b = wid>>10, wy = (wid>>5)&31, wx = wid&31;
  int t = threadIdx.x, wv = t>>6, lane = t&63;
  int g = lane>>4, c = lane&15;

  h16x8 afr[8];
  {
    int tok = 16*wv + c;
    size_t n = (size_t)(b*HD + wy*8 + (tok>>3))*WD + wx*8 + (tok&7);
    const short* yp = ybuf + n*CH;
    #pragma unroll
    for (int ks=0;ks<8;++ks)
      afr[ks] = *(const h16x8*)(yp + ks*32 + g*8);
  }
  {
    const short* wsrc = wqkv;
    #pragma unroll
    for (int i=0;i<12;++i){
      int rr = 24*wv + 2*i;
      int row = rr + (lane>>5);
      int colb = (lane&31)<<4;
      const short* gp = wsrc + row*256 + ((colb ^ ((row&7)<<4))>>1);
      __builtin_amdgcn_global_load_lds(
        (const __attribute__((address_space(1))) void*)gp,
        (__attribute__((address_space(3))) void*)(wlds + rr*256),
        16, 0, 0);
    }
  }
  __syncthreads();

  int s0 = c + 32*(g&1), s1 = s0 + 16;
  bool hiSel = (g & 2);

  f32x4 acc[4][4];
  #pragma unroll
  for (int mt=0;mt<4;++mt)
    #pragma unroll
    for (int nt=0;nt<4;++nt) acc[mt][nt] = (f32x4){0.f,0.f,0.f,0.f};

  #pragma unroll 1
  for (int hd=0; hd<8; ++hd){
    int cur = hd & 1;
    f32x4 qacc[6];
    #pragma unroll
    for (int nt=0;nt<6;++nt) qacc[nt] = (f32x4){0.f,0.f,0.f,0.f};
    #pragma unroll
    for (int nt=0; nt<6; ++nt){
      int R = nt*16 + c;
      const short* wr = wlds + R*256;
      int sw = (R&7)<<3;
      #pragma unroll
      for (int ks=0; ks<8; ++ks){
        h16x8 bf = *(const h16x8*)(wr + ((ks*32 + g*8) ^ sw));
        qacc[nt] = mfma_f16(afr[ks], bf, qacc[nt]);
      }
    }
    #pragma unroll
    for (int nt=0; nt<6; ++nt){
      float bias = qkvb[hd*96 + nt*16 + c];
      if (nt<4){
        #pragma unroll
        for (int j=0;j<4;++j){
          short hv = f2h(qacc[nt][j] + bias);
          int tok = 16*wv + 4*g + j;
          if (nt<2) qs[tok][nt*16 + c] = hv;
          else      ksm[tok][(nt-2)*16 + c] = hv;
        }
      } else {
        uint2 pk;
        pk.x = p2h(qacc[nt][0] + bias, qacc[nt][1] + bias);
        pk.y = p2h(qacc[nt][2] + bias, qacc[nt][3] + bias);
        *(uint2*)(&vT[(nt-4)*16 + c][16*wv + 4*g]) = pk;
      }
    }
    __syncthreads();
    if (hd < 7){
      const short* wsrc = wqkv + (size_t)(hd+1)*24576;
      #pragma unroll
      for (int i=0;i<12;++i){
        int rr = 24*wv + 2*i;
        int row = rr + (lane>>5);
        int colb = (lane&31)<<4;
        const short* gp = wsrc + row*256 + ((colb ^ ((row&7)<<4))>>1);
        __builtin_amdgcn_global_load_lds(
          (const __attribute__((address_space(1))) void*)gp,
          (__attribute__((address_space(3))) void*)(wlds + rr*256),
          16, 0, 0);
      }
    }
    f32x4 sv[4];
    h16x8 qa = *(const h16x8*)(&qs[16*wv + c][g*8]);
    #pragma unroll
    for (int nt=0;nt<4;++nt){
      h16x8 kb = *(const h16x8*)(&ksm[nt*16 + c][g*8]);
      f32x4 z = (f32x4){0.f,0.f,0.f,0.f};
      sv[nt] = mfma_f16(kb, qa, z);
    }
    float mx = sv[0][0];
    #pragma unroll
    for (int nt=0;nt<4;++nt)
      #pragma unroll
      for (int j=0;j<4;++j) mx = fmaxf(mx, sv[nt][j]);
    mx = fmaxf(mx, __shfl_xor(mx, 16));
    mx = fmaxf(mx, __shfl_xor(mx, 32));
    float sm = 0.f;
    #pragma unroll
    for (int nt=0;nt<4;++nt)
      #pragma unroll
      for (int j=0;j<4;++j){
        float e = __expf((sv[nt][j]-mx)*0.17677669529663687f);
        sv[nt][j] = e; sm += e;
      }
    sm += __shfl_xor(sm, 16);
    sm += __shfl_xor(sm, 32);
    float inv = 1.f/sm;
    unsigned pkLo[4], pkHi[4];
    #pragma unroll
    for (int nt=0;nt<4;++nt){
      pkLo[nt] = p2h(sv[nt][0], sv[nt][1]);
      pkHi[nt] = p2h(sv[nt][2], sv[nt][3]);
    }
    h16x8 pa[2];
    #pragma unroll
    for (int k2=0;k2<2;++k2){
      int n0 = 2*k2, n1 = 2*k2+1;
      unsigned w0a = __shfl((int)pkLo[n0], s0), w0b = __shfl((int)pkLo[n1], s0);
      unsigned w1a = __shfl((int)pkHi[n0], s0), w1b = __shfl((int)pkHi[n1], s0);
      unsigned w2a = __shfl((int)pkLo[n0], s1), w2b = __shfl((int)pkLo[n1], s1);
      unsigned w3a = __shfl((int)pkHi[n0], s1), w3b = __shfl((int)pkHi[n1], s1);
      union { unsigned u[4]; h16x8 v; } U;
      U.u[0] = hiSel ? w0b : w0a;
      U.u[1] = hiSel ? w1b : w1a;
      U.u[2] = hiSel ? w2b : w2a;
      U.u[3] = hiSel ? w3b : w3a;
      pa[k2] = U.v;
    }
    f32x4 ov[2];
    ov[0] = (f32x4){0.f,0.f,0.f,0.f}; ov[1] = (f32x4){0.f,0.f,0.f,0.f};
    #pragma unroll
    for (int k2=0;k2<2;++k2){
      #pragma unroll
      for (int nt=0;nt<2;++nt){
        h16x8 vb = *(const h16x8*)(&vT[nt*16 + c][k2*32 + g*8]);
        ov[nt] = mfma_f16(pa[k2], vb, ov[nt]);
      }
    }
    #pragma unroll
    for (int j=0;j<4;++j){
      float invO = __shfl(inv, 4*g + j);
      int tok = 16*wv + 4*g + j;
      o2[cur][tok][c]      = f2h(ov[0][j]*invO);
      o2[cur][tok][16 + c] = f2h(ov[1][j]*invO);
    }
    __syncthreads();
    #pragma unroll
    for (int mt=0;mt<4;++mt){
      h16x8 a = *(const h16x8*)(&o2[cur][mt*16+c][g*8]);
      #pragma unroll
      for (int nt=0;nt<4;++nt){
        h16x8 bfr = *(const h16x8*)(wproj + (size_t)(wv*64 + nt*16 + c)*256 + hd*32 + g*8);
        acc[mt][nt] = mfma_f16(a, bfr, acc[mt][nt]);
      }
    }
  }
  // ---- epilogue: bias + residual(f16 xc) + relu + LN3 -> zbuf (f16) ----
  #pragma unroll
  for (int mt=0;mt<4;++mt){
    #pragma unroll
    for (int j=0;j<4;++j){
      int row_l = mt*16 + 4*g + j;
      size_t n = (size_t)(b*HD + wy*8 + (row_l>>3))*WD + wx*8 + (row_l&7);
      float ps_ = 0.f, pq_ = 0.f;
      #pragma unroll
      for (int nt=0;nt<4;++nt){
        int col = wv*64 + nt*16 + c;
        float v = acc[mt][nt][j] + pb[col] + (float)xc[n*CH + col];
        v = fmaxf(v, 0.f);
        acc[mt][nt][j] = v;
        ps_ += v; pq_ += v*v;
      }
      #pragma unroll
      for (int o=1;o<16;o<<=1){ ps_ += __shfl_xor(ps_,o); pq_ += __shfl_xor(pq_,o); }
      if (c==0){ redS[row_l][wv] = ps_; redQ[row_l][wv] = pq_; }
    }
  }
  __syncthreads();
  #pragma unroll
  for (int mt=0;mt<4;++mt){
    #pragma unroll
    for (int j=0;j<4;++j){
      int row_l = mt*16 + 4*g + j;
      size_t n = (size_t)(b*HD + wy*8 + (row_l>>3))*WD + wx*8 + (row_l&7);
      float st = redS[row_l][0]+redS[row_l][1]+redS[row_l][2]+redS[row_l][3];
      float qt = redQ[row_l][0]+redQ[row_l][1]+redQ[row_l][2]+redQ[row_l][3];
      float mean = st*(1.f/CH);
      float rs = rsqrtf(qt*(1.f/CH) - mean*mean + 1e-5f);
      #pragma unroll
      for (int nt=0;nt<4;++nt){
        int col = wv*64 + nt*16 + c;
        float y = (acc[mt][nt][j]-mean)*rs*g3[col] + b3[col];
        zbuf[n*CH + col] = f2h(y);
      }
    }
  }
}

// ---------------- fused MLP: gelu(z@w1^T+b1)@w2^T+b2 -> f16 ----------------
__global__ __launch_bounds__(256) void k_mlp(const short* __restrict__ zbuf,
    const short* __restrict__ w1, const short* __restrict__ w2,
    const float* __restrict__ b1, const float* __restrict__ b2,
    __fp16* __restrict__ bsa){
  __shared__ short zt[16384];      // [64][256], byte col ^= (row&7)<<4
  __shared__ short hid[64][140];   // 280B stride == 6 banks mod 32
  int blk = blockIdx.x, t = threadIdx.x;
  int wv=t>>6, lane=t&63, g=lane>>4, c=lane&15;
  size_t m0 = (size_t)blk*64;
  {
    const short* zsrc = zbuf + m0*CH;
    #pragma unroll
    for (int i=0;i<8;++i){
      int rr = 16*wv + 2*i;
      int row = rr + (lane>>5);
      int colb = (lane&31)<<4;
      const short* gp = zsrc + row*256 + ((colb ^ ((row&7)<<4))>>1);
      __builtin_amdgcn_global_load_lds(
        (const __attribute__((address_space(1))) void*)gp,
        (__attribute__((address_space(3))) void*)(zt + rr*256),
        16, 0, 0);
    }
  }
  __syncthreads();
  f32x4 acc2[4][4];
  #pragma unroll
  for (int mt=0;mt<4;++mt)
    #pragma unroll
    for (int nt=0;nt<4;++nt) acc2[mt][nt] = (f32x4){0.f,0.f,0.f,0.f};
  #pragma unroll 1
  for (int hc=0; hc<8; ++hc){
    f32x4 a1[4][2];
    #pragma unroll
    for (int mt=0;mt<4;++mt){ a1[mt][0]=(f32x4){0.f,0.f,0.f,0.f}; a1[mt][1]=(f32x4){0.f,0.f,0.f,0.f}; }
    #pragma unroll 1
    for (int ks=0;ks<8;++ks){
      h16x8 a[4];
      #pragma unroll
      for (int mt=0;mt<4;++mt){
        int R = mt*16 + c;
        a[mt] = *(const h16x8*)(zt + R*256 + ((ks*32 + g*8) ^ ((R&7)<<3)));
      }
      #pragma unroll
      for (int nl=0;nl<2;++nl){
        int o = hc*128 + (wv*2+nl)*16 + c;
        h16x8 bfr = *(const h16x8*)(w1 + (size_t)o*256 + ks*32 + g*8);
        #pragma unroll
        for (int mt=0;mt<4;++mt)
          a1[mt][nl] = mfma_f16(a[mt], bfr, a1[mt][nl]);
      }
    }
    __syncthreads();   // A: prev hc's GEMM2 reads of hid complete
    #pragma unroll
    for (int mt=0;mt<4;++mt)
      #pragma unroll
      for (int nl=0;nl<2;++nl){
        int ol = (wv*2+nl)*16 + c;
        float bias = b1[hc*128 + ol];
        #pragma unroll
        for (int j=0;j<4;++j){
          float v = a1[mt][nl][j] + bias;
          float w = v*v;
          float tt = v*(1.5957691216f + 0.0713548162f*w);
          float e = __expf(-tt);
          float gv = v/(1.f + e);
          hid[mt*16 + 4*g + j][ol] = f2h(gv);
        }
      }
    __syncthreads();   // B: hid visible
    #pragma unroll 1
    for (int k2=0;k2<4;++k2){
      h16x8 a[4];
      #pragma unroll
      for (int mt=0;mt<4;++mt) a[mt] = *(const h16x8*)(&hid[mt*16+c][k2*32+g*8]);
      #pragma unroll
      for (int nt=0;nt<4;++nt){
        h16x8 bfr = *(const h16x8*)(w2 + (size_t)(wv*64+nt*16+c)*1024 + hc*128 + k2*32 + g*8);
        #pragma unroll
        for (int mt=0;mt<4;++mt)
          acc2[mt][nt] = mfma_f16(a[mt], bfr, acc2[mt][nt]);
      }
    }
  }
  #pragma unroll
  for (int mt=0;mt<4;++mt)
    #pragma unroll
    for (int nt=0;nt<4;++nt){
      int col = wv*64 + nt*16 + c;
      #pragma unroll
      for (int j=0;j<4;++j){
        int row_l = mt*16 + 4*g + j;
        bsa[(m0+row_l)*CH + col] = (__fp16)(acc2[mt][nt][j] + b2[col]);
      }
    }
}

// ---------------- depthwise 7x7 + bias + relu (f16 in -> f16 out) ----------------
__global__ __launch_bounds__(256) void k_dw7(const __fp16* __restrict__ src,
    const float* __restrict__ wT, const float* __restrict__ bias, __fp16* __restrict__ dst){
  int bid = blockIdx.x;
  int xg = bid & 63, yb = (bid>>6) & 31, b = bid>>11;
  int wv = threadIdx.x>>6, lane = threadIdx.x & 63;
  int xx = xg*4 + wv, y0 = yb*8;
  float4 bv = ((const float4*)bias)[lane];
  float4 acc[8];
  #pragma unroll
  for (int i=0;i<8;++i) acc[i] = bv;
  bool inty = (y0 >= 3) && (y0 <= HD-11);
  #pragma unroll 1
  for (int dx=0; dx<7; ++dx){
    int x2 = xx + dx - 3;
    bool vx = (unsigned)x2 < WD;
    float4 r[14];
    if (vx && inty){
      const __fp16* base = src + ((size_t)((b*HD + y0-3)*WD + x2))*CH + lane*4;
      #pragma unroll
      for (int k=0;k<14;++k){
        U8h H; H.u = *(const uint2*)(base + (size_t)k*WD*CH);
        r[k] = float4{(float)H.h[0][0], (float)H.h[0][1], (float)H.h[1][0], (float)H.h[1][1]};
      }
    } else {
      #pragma unroll
      for (int k=0;k<14;++k){
        int yy = y0 + k - 3;
        if (vx && (unsigned)yy < HD){
          U8h H; H.u = *(const uint2*)(src + ((size_t)((b*HD+yy)*WD + x2))*CH + lane*4);
          r[k] = float4{(float)H.h[0][0], (float)H.h[0][1], (float)H.h[1][0], (float)H.h[1][1]};
        } else r[k] = float4{0,0,0,0};
      }
    }
    #pragma unroll
    for (int dy=0; dy<7; ++dy){
      int wi = dy*7 + dx;
      float4 wv4 = ((const float4*)(wT + wi*256))[lane];
      #pragma unroll
      for (int yi=0; yi<8; ++yi){
        acc[yi].x += r[yi+dy].x * wv4.x;
        acc[yi].y += r[yi+dy].y * wv4.y;
        acc[yi].z += r[yi+dy].z * wv4.z;
        acc[yi].w += r[yi+dy].w * wv4.w;
      }
    }
  }
  #pragma unroll
  for (int yi=0; yi<8; ++yi){
    float4 o;
    o.x = fmaxf(acc[yi].x, 0.f); o.y = fmaxf(acc[yi].y, 0.f);
    o.z = fmaxf(acc[yi].z, 0.f); o.w = fmaxf(acc[yi].w, 0.f);
    size_t n = (size_t)((b*HD+y0+yi)*WD + xx);
    union { f16x2 h[2]; uint2 u; } P;
    P.h[0] = __builtin_amdgcn_cvt_pkrtz(o.x, o.y);
    P.h[1] = __builtin_amdgcn_cvt_pkrtz(o.z, o.w);
    *(uint2*)(dst + n*CH + lane*4) = P.u;
  }
}

// ---------------- merged: dw7-h (f16 in -> fp32 NHWC h_new) + convf (-> fp32 NCHW x_out) ----------------
__global__ __launch_bounds__(256) void k_dwf(const __fp16* __restrict__ src,
    const float* __restrict__ wTh7, const float* __restrict__ hbias,
    const float* __restrict__ wTf, const float* __restrict__ fbias,
    float* __restrict__ hout, float* __restrict__ xout){
  __shared__ float ot[4][8][65];
  int bid = blockIdx.x;
  int xg = bid & 63, yb = (bid>>6) & 31, b = bid>>11;
  int wv = threadIdx.x>>6, lane = threadIdx.x & 63;
  int xx = xg*4 + wv, y0 = yb*8;
  float4 bv = ((const float4*)hbias)[lane];
  float fbv = fbias[lane];
  float4 acc[8];
  float accf[8];
  #pragma unroll
  for (int i=0;i<8;++i){ acc[i] = bv; accf[i] = 0.f; }
  bool inty = (y0 >= 3) && (y0 <= HD-11);
  #pragma unroll 1
  for (int dx=0; dx<7; ++dx){
    int x2 = xx + dx - 3;
    bool vx = (unsigned)x2 < WD;
    float4 r[14];
    if (vx && inty){
      const __fp16* base = src + ((size_t)((b*HD + y0-3)*WD + x2))*CH + lane*4;
      #pragma unroll
      for (int k=0;k<14;++k){
        U8h H; H.u = *(const uint2*)(base + (size_t)k*WD*CH);
        r[k] = float4{(float)H.h[0][0], (float)H.h[0][1], (float)H.h[1][0], (float)H.h[1][1]};
      }
    } else {
      #pragma unroll
      for (int k=0;k<14;++k){
        int yy = y0 + k - 3;
        if (vx && (unsigned)yy < HD){
          U8h H; H.u = *(const uint2*)(src + ((size_t)((b*HD+yy)*WD + x2))*CH + lane*4);
          r[k] = float4{(float)H.h[0][0], (float)H.h[0][1], (float)H.h[1][0], (float)H.h[1][1]};
        } else r[k] = float4{0,0,0,0};
      }
    }
    #pragma unroll
    for (int dy=0; dy<7; ++dy){
      int wi = dy*7 + dx;
      float4 wv4 = ((const float4*)(wTh7 + wi*256))[lane];
      #pragma unroll
      for (int yi=0; yi<8; ++yi){
        acc[yi].x += r[yi+dy].x * wv4.x;
        acc[yi].y += r[yi+dy].y * wv4.y;
        acc[yi].z += r[yi+dy].z * wv4.z;
        acc[yi].w += r[yi+dy].w * wv4.w;
      }
    }
    if (dx >= 2 && dx <= 4){
      int fdx = dx - 2;
      #pragma unroll
      for (int dy=0; dy<3; ++dy){
        float4 w4 = ((const float4*)(wTf + (dy*3+fdx)*256))[lane];
        #pragma unroll
        for (int yi=0; yi<8; ++yi){
          float4 rv = r[yi+dy+2];
          accf[yi] += rv.x*w4.x + rv.y*w4.y + rv.z*w4.z + rv.w*w4.w;
        }
      }
    }
  }
  #pragma unroll
  for (int yi=0; yi<8; ++yi){
    float4 o;
    o.x = fmaxf(acc[yi].x, 0.f); o.y = fmaxf(acc[yi].y, 0.f);
    o.z = fmaxf(acc[yi].z, 0.f); o.w = fmaxf(acc[yi].w, 0.f);
    ((float4*)(hout + ((size_t)((b*HD+y0+yi)*WD + xx))*CH))[lane] = o;
  }
  #pragma unroll
  for (int yi=0; yi<8; ++yi) ot[wv][yi][lane] = fmaxf(accf[yi] + fbv, 0.f);
  __syncthreads();
  #pragma unroll
  for (int rep=0; rep<2; ++rep){
    int p = rep*256 + threadIdx.x;
    int oc = p>>3, yi = p&7;
    float4 v;
    v.x = ot[0][yi][oc]; v.y = ot[1][yi][oc]; v.z = ot[2][yi][oc]; v.w = ot[3][yi][oc];
    *(float4*)(xout + (((size_t)(b*64+oc))*HD + y0+yi)*WD + xg*4) = v;
  }
}

extern "C" void kernel_launch(void* const* d_in, const int* in_sizes, int n_in,
                              void* d_out, int out_size, void* d_ws, size_t ws_size,
                              hipStream_t stream) {
  const float* x      = (const float*)d_in[0];
  const float* hbuf   = (const float*)d_in[1];
  const float* conv_w = (const float*)d_in[2];
  const float* conv_b = (const float*)d_in[3];
  const float* comb_w = (const float*)d_in[4];
  const float* comb_b = (const float*)d_in[5];
  const float* ln1_g  = (const float*)d_in[6];
  const float* ln1_b  = (const float*)d_in[7];
  const float* ln2_g  = (const float*)d_in[8];
  const float* ln2_b  = (const float*)d_in[9];
  const float* ln3_g  = (const float*)d_in[10];
  const float* ln3_b  = (const float*)d_in[11];
  const float* fsa_g  = (const float*)d_in[12];
  const float* fsa_b  = (const float*)d_in[13];
  const float* qkv_w  = (const float*)d_in[14];
  const float* qkv_b  = (const float*)d_in[15];
  const float* proj_w = (const float*)d_in[16];
  const float* proj_b = (const float*)d_in[17];
  const float* mlp_w1 = (const float*)d_in[18];
  const float* mlp_b1 = (const float*)d_in[19];
  const float* mlp_w2 = (const float*)d_in[20];
  const float* mlp_b2 = (const float*)d_in[21];
  const float* convg_w= (const float*)d_in[22];
  const float* convg_b= (const float*)d_in[23];
  const float* convh_w= (const float*)d_in[24];
  const float* convh_b= (const float*)d_in[25];
  const float* convf_w= (const float*)d_in[26];
  const float* convf_b= (const float*)d_in[27];
  float* out = (float*)d_out;
  char* ws = (char*)d_ws;

  short* xcv  = (short*)(ws);
  short* hh   = (short*)(ws + 67108864);
  short* zbuf = (short*)(ws + 67108864);
  short* xch  = (short*)(ws + 134217728);
  __fp16* bsa = (__fp16*)(ws + 134217728);
  short* ybuf = (short*)(ws + 268435456);
  __fp16* gbuf= (__fp16*)(ws + 335544320);
  short* wb   = (short*)(ws + 469762048);
  float* wT   = (float*)(ws + 471334912);
  short* wTh  = (short*)wT + 104960;

  k_prep<<<19759,256,0,stream>>>(qkv_w, proj_w, mlp_w1, mlp_w2, wb,
                                 comb_w, convg_w, convh_w, convf_w, wT, hbuf, hh);
  k_conv3<<<8192,256,0,stream>>>(x, conv_w, conv_b, ln1_g, ln1_b, xcv);
  k_comb<<<8192,256,0,stream>>>(xcv, hh, wTh, comb_b, ln2_g, ln2_b, fsa_g, fsa_b, xch, ybuf);
  k_attn<<<2048,256,0,stream>>>(ybuf, wb, qkv_b, wb+196608, proj_b, (const __fp16*)xch, ln3_g, ln3_b, zbuf);
  k_mlp<<<2048,256,0,stream>>>(zbuf, wb+262144, wb+524288, mlp_b1, mlp_b2, bsa);
  k_dw7<<<4096,256,0,stream>>>(bsa, wT+25088, convg_b, gbuf);
  k_dwf<<<4096,256,0,stream>>>(gbuf, wT+37632, convh_b, wT+50176, convf_b, out + 8388608, out);
}